// Round 16
// baseline (525.128 us; speedup 1.0000x reference)
//
#include <hip/hip_runtime.h>
#include <hip/hip_bf16.h>
#include <math.h>
#include <stddef.h>
#include <stdint.h>

#define TOKS 4096
#define DIM  1024
#define FF   4096
#define NEXP 8
#define NHEAD 16
#define HDIM 64
#define SEQ  1024
#define NBATCH 4
#define MAXSLOTS 9216
#define MAXTILES 72

// Swizzled tile-major layout for GEMM operands: logical [M][K] stored as
// [(r>>7)][(k>>6)] tiles of 8192 elems; elem (r,k) at
// ((r>>7)*(K>>6) + (k>>6))*8192 + (r&127)*64 + ((k&63) ^ ((r&7)<<3)).

typedef __attribute__((ext_vector_type(8))) short short8;   // 8 bf16
typedef __attribute__((ext_vector_type(4))) float f32x4;
typedef unsigned short u16;

__device__ __forceinline__ u16 f2bf(float f) {
    __hip_bfloat16 b = __float2bfloat16(f);
    return *reinterpret_cast<u16*>(&b);
}

__device__ __forceinline__ float bf2f(u16 u) {
    __hip_bfloat16 b = *reinterpret_cast<__hip_bfloat16*>(&u);
    return __bfloat162float(b);
}

__device__ __forceinline__ int tswz(int row, int col) {
    return col ^ ((row & 7) << 3);
}

__device__ __forceinline__ float gelu_fast(float x) {
    float s = x * x;
    float t = x * fmaf(s, 0.0713548162f, 1.5957691216f);
    float e = __expf(-t);
    return x * __builtin_amdgcn_rcpf(1.f + e);
}

// async global->LDS, 16 bytes/lane (LDS dest linear: base + lane*16)
__device__ __forceinline__ void gl2lds16(const void* g, void* l) {
    __builtin_amdgcn_global_load_lds((const __attribute__((address_space(1))) void*)g,
                                     (__attribute__((address_space(3))) void*)l,
                                     16, 0, 0);
}

// ---------------- RMSNorm (+ optional fused router, + optional fused residual-combine) ----------------
template <int ROUTER, int TM, int RES>
__global__ __launch_bounds__(256) void rmsnorm_k(const float* __restrict__ x,
                                                 const float* __restrict__ w,
                                                 u16* __restrict__ ob,
                                                 const float* __restrict__ wr,
                                                 int* __restrict__ esel,
                                                 float2* __restrict__ wsel,
                                                 float* __restrict__ zz,
                                                 float* __restrict__ pp,
                                                 const u16* __restrict__ resP,
                                                 float* __restrict__ xo_out) {
    int t = blockIdx.x, tid = threadIdx.x;
    float4 xv = reinterpret_cast<const float4*>(x + (size_t)t * DIM)[tid];
    if (RES) {
        const size_t NTD = (size_t)TOKS * DIM;
        size_t d4 = (size_t)t * DIM + tid * 4;
        #pragma unroll
        for (int ks = 0; ks < RES; ++ks) {
            ushort4 v = *reinterpret_cast<const ushort4*>(resP + ks * NTD + d4);
            xv.x += bf2f(v.x); xv.y += bf2f(v.y); xv.z += bf2f(v.z); xv.w += bf2f(v.w);
        }
        *reinterpret_cast<float4*>(xo_out + d4) = xv;
    }
    float ss = xv.x * xv.x + xv.y * xv.y + xv.z * xv.z + xv.w * xv.w;
    #pragma unroll
    for (int off = 32; off; off >>= 1) ss += __shfl_xor(ss, off);
    __shared__ float red[4];
    if ((tid & 63) == 0) red[tid >> 6] = ss;
    __syncthreads();
    float tot = red[0] + red[1] + red[2] + red[3];
    float scale = rsqrtf(tot * (1.0f / (float)DIM) + 1e-5f);
    float4 wv = reinterpret_cast<const float4*>(w)[tid];
    float4 ov;
    ov.x = xv.x * scale * wv.x;
    ov.y = xv.y * scale * wv.y;
    ov.z = xv.z * scale * wv.z;
    ov.w = xv.w * scale * wv.w;
    ushort4 pk;
    pk.x = f2bf(ov.x); pk.y = f2bf(ov.y); pk.z = f2bf(ov.z); pk.w = f2bf(ov.w);
    if (TM) {
        size_t addr = ((size_t)(t >> 7) * 16 + (tid >> 4)) * 8192 +
                      (size_t)(t & 127) * 64 + tswz(t, (tid * 4) & 63);
        *reinterpret_cast<ushort4*>(ob + addr) = pk;
    } else {
        *reinterpret_cast<ushort4*>(ob + (size_t)t * DIM + tid * 4) = pk;
    }

    if (ROUTER) {
        int d0 = tid * 4;
        const float* wp = wr + (size_t)d0 * NEXP;
        float pl[8];
        float4 a0 = *reinterpret_cast<const float4*>(wp + 0);
        float4 a1 = *reinterpret_cast<const float4*>(wp + 4);
        float4 b0 = *reinterpret_cast<const float4*>(wp + 8);
        float4 b1 = *reinterpret_cast<const float4*>(wp + 12);
        float4 c0 = *reinterpret_cast<const float4*>(wp + 16);
        float4 c1 = *reinterpret_cast<const float4*>(wp + 20);
        float4 d0v = *reinterpret_cast<const float4*>(wp + 24);
        float4 d1v = *reinterpret_cast<const float4*>(wp + 28);
        pl[0] = ov.x * a0.x + ov.y * b0.x + ov.z * c0.x + ov.w * d0v.x;
        pl[1] = ov.x * a0.y + ov.y * b0.y + ov.z * c0.y + ov.w * d0v.y;
        pl[2] = ov.x * a0.z + ov.y * b0.z + ov.z * c0.z + ov.w * d0v.z;
        pl[3] = ov.x * a0.w + ov.y * b0.w + ov.z * c0.w + ov.w * d0v.w;
        pl[4] = ov.x * a1.x + ov.y * b1.x + ov.z * c1.x + ov.w * d1v.x;
        pl[5] = ov.x * a1.y + ov.y * b1.y + ov.z * c1.y + ov.w * d1v.y;
        pl[6] = ov.x * a1.z + ov.y * b1.z + ov.z * c1.z + ov.w * d1v.z;
        pl[7] = ov.x * a1.w + ov.y * b1.w + ov.z * c1.w + ov.w * d1v.w;
        #pragma unroll
        for (int e = 0; e < 8; ++e) {
            #pragma unroll
            for (int off = 32; off; off >>= 1) pl[e] += __shfl_xor(pl[e], off);
        }
        __shared__ float red2[4][8];
        if ((tid & 63) == 0) {
            #pragma unroll
            for (int e = 0; e < 8; ++e) red2[tid >> 6][e] = pl[e];
        }
        __syncthreads();
        if (tid == 0) {
            float lg[8];
            #pragma unroll
            for (int e = 0; e < 8; ++e)
                lg[e] = red2[0][e] + red2[1][e] + red2[2][e] + red2[3][e];
            float mx = lg[0];
            #pragma unroll
            for (int e = 1; e < 8; ++e) mx = fmaxf(mx, lg[e]);
            float p[8], se = 0.f;
            #pragma unroll
            for (int e = 0; e < 8; ++e) { p[e] = __expf(lg[e] - mx); se += p[e]; }
            float inv = 1.f / se;
            #pragma unroll
            for (int e = 0; e < 8; ++e) p[e] *= inv;
            int i0 = 0;
            #pragma unroll
            for (int e = 1; e < 8; ++e) if (p[e] > p[i0]) i0 = e;
            int i1 = (i0 == 0) ? 1 : 0;
            #pragma unroll
            for (int e = 0; e < 8; ++e) if (e != i0 && p[e] > p[i1]) i1 = e;
            float w0 = p[i0], w1 = p[i1], s = w0 + w1;
            esel[t] = i0 | (i1 << 8);
            wsel[t] = make_float2(w0 / s, w1 / s);
            float z = mx + logf(se);
            zz[t] = z * z;
            #pragma unroll
            for (int e = 0; e < 8; ++e) pp[(size_t)t * 8 + e] = p[e];
        }
    }
}

// ---------------- tconv body: in[K][N] fp32 slab -> out swizzled tile-major [N][K] bf16 ----------------
__device__ __forceinline__ void tconv_body(const float* __restrict__ ip,
                                           u16* __restrict__ op,
                                           int K, int N, int r0, int c0, int t) {
    __shared__ float tile[64][65];
    #pragma unroll
    for (int i = 0; i < 4; ++i) {
        int r = (t >> 4) + i * 16;
        float4 v = *reinterpret_cast<const float4*>(&ip[(size_t)(r0 + r) * N + c0 + (t & 15) * 4]);
        tile[r][(t & 15) * 4 + 0] = v.x;
        tile[r][(t & 15) * 4 + 1] = v.y;
        tile[r][(t & 15) * 4 + 2] = v.z;
        tile[r][(t & 15) * 4 + 3] = v.w;
    }
    __syncthreads();
    int c = t >> 2, rr = (t & 3) * 16;
    short8 v0, v1;
    #pragma unroll
    for (int u = 0; u < 8; ++u) v0[u] = (short)f2bf(tile[rr + u][c]);
    #pragma unroll
    for (int u = 0; u < 8; ++u) v1[u] = (short)f2bf(tile[rr + 8 + u][c]);
    int n = c0 + c;
    int k = r0 + rr;
    size_t tb = ((size_t)(n >> 7) * (K >> 6) + (k >> 6)) * 8192 + (size_t)(n & 127) * 64;
    *reinterpret_cast<short8*>(&op[tb + tswz(n, k & 63)]) = v0;
    *reinterpret_cast<short8*>(&op[tb + tswz(n, (k + 8) & 63)]) = v1;
}

__global__ __launch_bounds__(256) void tconv_k(const float* __restrict__ in,
                                               u16* __restrict__ out,
                                               int K, int N) {
    tconv_body(in, out, K, N, blockIdx.y * 64, blockIdx.x * 64, threadIdx.x);
}

__global__ __launch_bounds__(256) void tconvE_k(const float* __restrict__ w1,
                                                const float* __restrict__ w2,
                                                u16* __restrict__ w1T,
                                                u16* __restrict__ w2T) {
    int bid = blockIdx.x;
    int half = bid >> 13;
    int eb = bid & 8191;
    int e = eb >> 10;
    int t = eb & 1023;
    const size_t ED = (size_t)DIM * FF;
    if (half == 0) {
        int bxx = t & 63, byy = t >> 6;
        tconv_body(w1 + (size_t)e * ED, w1T + (size_t)e * ED,
                   DIM, FF, byy * 64, bxx * 64, threadIdx.x);
    } else {
        int bxx = t & 15, byy = t >> 4;
        tconv_body(w2 + (size_t)e * ED, w2T + (size_t)e * ED,
                   FF, DIM, byy * 64, bxx * 64, threadIdx.x);
    }
}

// ---------------- V transpose per head: vb[B*S][D] bf16 -> vt[BH][64][S] ----------------
__global__ __launch_bounds__(256) void vtrans_k(const u16* __restrict__ vb,
                                                u16* __restrict__ vt) {
    __shared__ u16 tile[64][80];
    int bh = blockIdx.y;
    int b = bh >> 4, h = bh & 15;
    int s0 = blockIdx.x * 64;
    int t = threadIdx.x;
    #pragma unroll
    for (int i = 0; i < 2; ++i) {
        int chunk = i * 256 + t;
        int r = chunk >> 3;
        int c = (chunk & 7) * 8;
        short8 v = *reinterpret_cast<const short8*>(
            &vb[(size_t)(b * SEQ + s0 + r) * DIM + h * HDIM + c]);
        *reinterpret_cast<short8*>(&tile[r][c]) = v;
    }
    __syncthreads();
    int d = t >> 2, s16 = (t & 3) * 16;
    short8 o0, o1;
    #pragma unroll
    for (int u = 0; u < 8; ++u) o0[u] = (short)tile[s16 + u][d];
    #pragma unroll
    for (int u = 0; u < 8; ++u) o1[u] = (short)tile[s16 + 8 + u][d];
    size_t ob = ((size_t)bh * HDIM + d) * SEQ + s0 + s16;
    *reinterpret_cast<short8*>(&vt[ob]) = o0;
    *reinterpret_cast<short8*>(&vt[ob + 8]) = o1;
}

// ---------------- Gather: hg[slot] = h2b[slot_tok[slot]] in swizzled tile-major ----------------
__global__ __launch_bounds__(256) void gather_k(const u16* __restrict__ h2b,
                                                const int* __restrict__ slot_tok,
                                                const int* __restrict__ hdr,
                                                u16* __restrict__ hg) {
    int s = blockIdx.x * 4 + (threadIdx.x >> 6);
    if (s >= (hdr[0] << 7)) return;
    int lane = threadIdx.x & 63;
    int tok = slot_tok[s];
    const short8* src = reinterpret_cast<const short8*>(h2b + (size_t)tok * DIM + lane * 16);
    size_t tb = ((size_t)(s >> 7) * 16 + (lane >> 2)) * 8192 + (size_t)(s & 127) * 64;
    int col = (lane * 16) & 63;
    short8 v0 = src[0], v1 = src[1];
    *reinterpret_cast<short8*>(hg + tb + tswz(s, col)) = v0;
    *reinterpret_cast<short8*>(hg + tb + tswz(s, col + 8)) = v1;
}

// ---------------- MFMA GEMM: double-buffered single-barrier, swz tile-major, XCD supertiling, split-K ----------------
// Per K-step: stage(next tile -> buf^1) ; compute(buf) ; __syncthreads (drains prefetch); swap.
// MODE 0: fused QKV; MODE 1: wo bf16 partials; MODE 2: gelu swz-tile out; MODE 3: bf16 partials.
template <int MODE, int GX, int SPLITK, int PX>
__global__ __launch_bounds__(256) void mgemm(const u16* __restrict__ A,
                                             const u16* __restrict__ Bt,
                                             void* __restrict__ C0,
                                             void* __restrict__ C1,
                                             void* __restrict__ C2,
                                             const int* __restrict__ hdr,
                                             int K, int N, size_t part_stride) {
    __shared__ __align__(16) u16 As[2][128 * 64];
    __shared__ __align__(16) u16 Bs[2][128 * 64];
    const int tid = threadIdx.x;
    const int lane = tid & 63;
    const int w = tid >> 6;
    const int wr = w >> 1, wc = w & 1;
    const int lo = lane & 15, hi = lane >> 4;

    // XCD supertile mapping
    const int PY = 8 / PX;
    const int LBX = GX / PX;
    const int LBY = (int)gridDim.y / PY;
    int f = (int)blockIdx.y * GX + (int)blockIdx.x;
    int xcd = f & 7;
    int j = f >> 3;
    int cx = xcd % PX, cy = xcd / PX;
    int lbx = j % LBX, lby = j / LBX;
    const int bx = cx * LBX + lbx;
    const int by_raw = cy * LBY + lby;
    const int TY = (int)gridDim.y / SPLITK;
    const int ksid = by_raw / TY;
    const int by = by_raw % TY;

    if (MODE >= 2) {
        if (by >= hdr[0]) return;
    }
    const u16* Bbase;
    if (MODE >= 2) {
        int e = hdr[1 + by];
        Bbase = Bt + (size_t)e * N * K + (size_t)bx * 128 * K;
    } else {
        Bbase = Bt + (size_t)bx * 128 * K;
    }
    const size_t row0 = (size_t)by * 128;
    const u16* Abase = A + row0 * K;

    f32x4 acc[4][4];
    #pragma unroll
    for (int m = 0; m < 4; ++m)
        #pragma unroll
        for (int n = 0; n < 4; ++n) acc[m][n] = (f32x4){0.f, 0.f, 0.f, 0.f};

    const int KS = K / SPLITK;
    const int kb = ksid * KS;
    const int nt = KS >> 6;

    auto stage = [&](int buf, int k0) {
        const u16* at = Abase + (size_t)k0 * 128;
        const u16* bt = Bbase + (size_t)k0 * 128;
        #pragma unroll
        for (int i = 0; i < 4; ++i) {
            int chunk = i * 256 + tid;
            gl2lds16(at + chunk * 8, &As[buf][chunk * 8]);
        }
        #pragma unroll
        for (int i = 0; i < 4; ++i) {
            int chunk = i * 256 + tid;
            gl2lds16(bt + chunk * 8, &Bs[buf][chunk * 8]);
        }
    };

    stage(0, kb);
    __syncthreads();

    int cur = 0;
    for (int t = 0; t < nt; ++t) {
        if (t + 1 < nt) stage(cur ^ 1, kb + ((t + 1) << 6));   // prefetch next tile
        const u16* Asl = As[cur];
        const u16* Bsl = Bs[cur];
        #pragma unroll
        for (int ks = 0; ks < 2; ++ks) {
            short8 a[4], b[4];
            #pragma unroll
            for (int m = 0; m < 4; ++m) {
                int row = wr * 64 + m * 16 + lo;
                a[m] = *reinterpret_cast<const short8*>(
                    &Asl[row * 64 + tswz(row, ks * 32 + hi * 8)]);
            }
            #pragma unroll
            for (int n = 0; n < 4; ++n) {
                int row = wc * 64 + n * 16 + lo;
                b[n] = *reinterpret_cast<const short8*>(
                    &Bsl[row * 64 + tswz(row, ks * 32 + hi * 8)]);
            }
            #pragma unroll
            for (int m = 0; m < 4; ++m)
                #pragma unroll
                for (int n = 0; n < 4; ++n)
                    acc[m][n] = __builtin_amdgcn_mfma_f32_16x16x32_bf16(a[m], b[n], acc[m][n], 0, 0, 0);
        }
        __syncthreads();   // drains prefetch (vmcnt 0 + lgkm) + barrier
        cur ^= 1;
    }

    u16* Pf = (u16*)C0 + (size_t)ksid * part_stride;
    #pragma unroll
    for (int m = 0; m < 4; ++m) {
        #pragma unroll
        for (int j2 = 0; j2 < 4; ++j2) {
            int rloc = wr * 64 + m * 16 + hi * 4 + j2;
            size_t r = row0 + rloc;
            #pragma unroll
            for (int n = 0; n < 4; ++n) {
                float v = acc[m][n][j2];
                if (MODE == 0) {
                    int sel = bx >> 3;
                    size_t ccl = (size_t)((bx & 7) * 128 + wc * 64 + n * 16 + lo);
                    u16* Cp = (sel == 0) ? (u16*)C0 : (sel == 1) ? (u16*)C1 : (u16*)C2;
                    Cp[r * N + ccl] = f2bf(v);
                } else if (MODE == 2) {
                    size_t tile = (size_t)by * (N >> 6) + (size_t)bx * 2 + wc;
                    ((u16*)C0)[tile * 8192 + (size_t)rloc * 64 + tswz(rloc, n * 16 + lo)] =
                        f2bf(gelu_fast(v));
                } else {
                    size_t cc = (size_t)(bx * 128 + wc * 64 + n * 16 + lo);
                    Pf[r * N + cc] = f2bf(v);
                }
            }
        }
    }
}

// ---------------- Flash attention (LDS-staged K/V, online softmax, swz ctx out) ----------------
__global__ __launch_bounds__(256) void fattn(const u16* __restrict__ Q,
                                             const u16* __restrict__ Kb,
                                             const u16* __restrict__ Vt,
                                             u16* __restrict__ O) {
    __shared__ __align__(16) char Ks[64 * 128];
    __shared__ __align__(16) char Vs[64 * 128];
    __shared__ __align__(16) char Ps[4][16 * 128];
    const int tid = threadIdx.x, lane = tid & 63, w = tid >> 6;
    const int lo = lane & 15, hi = lane >> 4;
    int fb = (int)blockIdx.x;
    fb = (fb & 7) * ((NBATCH * NHEAD * (SEQ / 64)) >> 3) + (fb >> 3);
    const int qt = fb & 15;
    const int bh = fb >> 4;
    const int b = bh >> 4, h = bh & 15;

    size_t qtok = (size_t)(b * SEQ + qt * 64 + w * 16 + lo);
    short8 qf[2];
    #pragma unroll
    for (int ks = 0; ks < 2; ++ks)
        qf[ks] = *reinterpret_cast<const short8*>(&Q[qtok * DIM + h * HDIM + ks * 32 + hi * 8]);

    float m_r[4], l_r[4];
    f32x4 oa[4];
    #pragma unroll
    for (int j = 0; j < 4; ++j) { m_r[j] = -1e30f; l_r[j] = 0.f; }
    #pragma unroll
    for (int n = 0; n < 4; ++n) oa[n] = (f32x4){0.f, 0.f, 0.f, 0.f};

    const size_t kbase = ((size_t)b * SEQ) * DIM + h * HDIM;
    const size_t vbase = ((size_t)bh * HDIM) * SEQ;
    char* P = Ps[w];

    for (int kt = 0; kt < 16; ++kt) {
        __syncthreads();
        #pragma unroll
        for (int i = 0; i < 2; ++i) {
            int chunk = i * 256 + tid;
            int r = chunk >> 3;
            int cb = (chunk & 7) << 4;
            short8 v = *reinterpret_cast<const short8*>(
                &Kb[kbase + (size_t)(kt * 64 + r) * DIM + (cb >> 1)]);
            *reinterpret_cast<short8*>(&Ks[r * 128 + (cb ^ ((r & 7) << 4))]) = v;
        }
        #pragma unroll
        for (int i = 0; i < 2; ++i) {
            int chunk = i * 256 + tid;
            int r = chunk >> 3;
            int cb = (chunk & 7) << 4;
            short8 v = *reinterpret_cast<const short8*>(
                &Vt[vbase + (size_t)r * SEQ + kt * 64 + (cb >> 1)]);
            *reinterpret_cast<short8*>(&Vs[r * 128 + (cb ^ ((r & 7) << 4))]) = v;
        }
        __syncthreads();

        f32x4 s[4];
        #pragma unroll
        for (int n = 0; n < 4; ++n) {
            f32x4 z = {0.f, 0.f, 0.f, 0.f};
            #pragma unroll
            for (int ks = 0; ks < 2; ++ks) {
                int row = n * 16 + lo;
                int cb = (ks * 32 + hi * 8) * 2;
                short8 kf = *reinterpret_cast<const short8*>(
                    &Ks[row * 128 + (cb ^ ((row & 7) << 4))]);
                z = __builtin_amdgcn_mfma_f32_16x16x32_bf16(qf[ks], kf, z, 0, 0, 0);
            }
            s[n] = z * 0.125f;
        }

        float mx[4];
        #pragma unroll
        for (int j = 0; j < 4; ++j) {
            mx[j] = fmaxf(fmaxf(s[0][j], s[1][j]), fmaxf(s[2][j], s[3][j]));
            #pragma unroll
            for (int off = 1; off < 16; off <<= 1) mx[j] = fmaxf(mx[j], __shfl_xor(mx[j], off));
        }
        float corr[4], rsum[4];
        #pragma unroll
        for (int j = 0; j < 4; ++j) {
            float mn = fmaxf(m_r[j], mx[j]);
            corr[j] = __expf(m_r[j] - mn);
            m_r[j] = mn;
            rsum[j] = 0.f;
        }
        #pragma unroll
        for (int n = 0; n < 4; ++n)
            #pragma unroll
            for (int j = 0; j < 4; ++j) {
                float p = __expf(s[n][j] - m_r[j]);
                s[n][j] = p;
                rsum[j] += p;
            }
        #pragma unroll
        for (int j = 0; j < 4; ++j) {
            #pragma unroll
            for (int off = 1; off < 16; off <<= 1) rsum[j] += __shfl_xor(rsum[j], off);
            l_r[j] = l_r[j] * corr[j] + rsum[j];
        }
        #pragma unroll
        for (int n = 0; n < 4; ++n)
            #pragma unroll
            for (int j = 0; j < 4; ++j) oa[n][j] *= corr[j];

        #pragma unroll
        for (int n = 0; n < 4; ++n)
            #pragma unroll
            for (int j = 0; j < 4; ++j) {
                int q = hi * 4 + j;
                int key = n * 16 + lo;
                *reinterpret_cast<u16*>(&P[q * 128 + ((key * 2) ^ ((q & 7) << 4))]) =
                    f2bf(s[n][j]);
            }

        #pragma unroll
        for (int ks = 0; ks < 2; ++ks) {
            int keyb = (ks * 32 + hi * 8) * 2;
            short8 pf = *reinterpret_cast<const short8*>(
                &P[lo * 128 + (keyb ^ ((lo & 7) << 4))]);
            #pragma unroll
            for (int n = 0; n < 4; ++n) {
                int d = n * 16 + lo;
                short8 vf = *reinterpret_cast<const short8*>(
                    &Vs[d * 128 + (keyb ^ ((d & 7) << 4))]);
                oa[n] = __builtin_amdgcn_mfma_f32_16x16x32_bf16(pf, vf, oa[n], 0, 0, 0);
            }
        }
    }

    #pragma unroll
    for (int j = 0; j < 4; ++j) l_r[j] = 1.f / l_r[j];
    int otok = b * SEQ + qt * 64 + w * 16;
    #pragma unroll
    for (int n = 0; n < 4; ++n)
        #pragma unroll
        for (int j = 0; j < 4; ++j) {
            int r = otok + hi * 4 + j;
            size_t addr = ((size_t)(r >> 7) * 16 + h) * 8192 +
                          (size_t)(r & 127) * 64 + tswz(r, n * 16 + lo);
            O[addr] = f2bf(oa[n][j] * l_r[j]);
        }
}

// ---------------- Scheduler + loss ----------------
__global__ __launch_bounds__(256) void sched_k(const int* __restrict__ esel,
                                               const float2* __restrict__ wsel,
                                               const float* __restrict__ zz,
                                               const float* __restrict__ pp,
                                               int* __restrict__ hdr,
                                               int* __restrict__ slot_tok,
                                               float* __restrict__ slot_w,
                                               int2* __restrict__ tslot,
                                               float* __restrict__ loss_out) {
    __shared__ int cnt[8], base[8], cur[8], tot_s;
    __shared__ float lred[4][9];
    int tid = threadIdx.x;
    if (tid < 8) { cnt[tid] = 0; cur[tid] = 0; }
    __syncthreads();
    for (int t = tid; t < TOKS; t += 256) {
        int es = esel[t];
        atomicAdd(&cnt[es & 255], 1);
        atomicAdd(&cnt[(es >> 8) & 255], 1);
    }
    __syncthreads();
    if (tid == 0) {
        int run = 0;
        for (int e = 0; e < 8; ++e) {
            base[e] = run;
            run += (cnt[e] + 127) & ~127;
        }
        tot_s = run;
        hdr[0] = run >> 7;
    }
    __syncthreads();
    int ntiles = tot_s >> 7;
    for (int T = tid; T < ntiles; T += 256) {
        int r = T << 7;
        int e = 0;
        for (int k = 1; k < 8; ++k) if (r >= base[k]) e = k;
        hdr[1 + T] = e;
    }
    for (int t = tid; t < TOKS; t += 256) {
        int es = esel[t];
        float2 ww = wsel[t];
        int e0 = es & 255, e1 = (es >> 8) & 255;
        int s0 = base[e0] + atomicAdd(&cur[e0], 1);
        slot_tok[s0] = t; slot_w[s0] = ww.x;
        int s1 = base[e1] + atomicAdd(&cur[e1], 1);
        slot_tok[s1] = t; slot_w[s1] = ww.y;
        tslot[t] = make_int2(s0, s1);
    }
    __syncthreads();
    for (int idx = tid; idx < 8 * 128; idx += 256) {
        int e = idx >> 7, p2 = idx & 127;
        int c = cnt[e];
        int al = (c + 127) & ~127;
        if (c + p2 < al) {
            int s = base[e] + c + p2;
            slot_tok[s] = 0;
            slot_w[s] = 0.f;
        }
    }
    // router loss
    float sz = 0.f, sp[8] = {0, 0, 0, 0, 0, 0, 0, 0};
    for (int t = tid; t < TOKS; t += 256) {
        sz += zz[t];
        #pragma unroll
        for (int e = 0; e < 8; ++e) sp[e] += pp[(size_t)t * 8 + e];
    }
    #pragma unroll
    for (int off = 32; off; off >>= 1) {
        sz += __shfl_xor(sz, off);
        #pragma unroll
        for (int e = 0; e < 8; ++e) sp[e] += __shfl_xor(sp[e], off);
    }
    if ((tid & 63) == 0) {
        lred[tid >> 6][0] = sz;
        #pragma unroll
        for (int e = 0; e < 8; ++e) lred[tid >> 6][1 + e] = sp[e];
    }
    __syncthreads();
    if (tid == 0) {
        float tz = lred[0][0] + lred[1][0] + lred[2][0] + lred[3][0];
        float loss = 0.001f * (tz / (float)TOKS);
        float s = 0.f;
        for (int e = 0; e < 8; ++e) {
            float mp = (lred[0][1 + e] + lred[1][1 + e] + lred[2][1 + e] + lred[3][1 + e]) / (float)TOKS;
            s += mp * ((float)cnt[e] / (float)TOKS);
        }
        loss_out[0] = loss + (float)NEXP * s;
    }
}

// ---------------- Combine MoE: xo[tok] += sum over NP bf16 K-partials, 2 slots ----------------
template <int NP>
__global__ __launch_bounds__(256) void combine_k(const u16* __restrict__ accP,
                                                 const int2* __restrict__ tslot,
                                                 const float2* __restrict__ wsel,
                                                 float* __restrict__ xo) {
    int t = blockIdx.x;
    int d4 = threadIdx.x * 4;
    int2 s = tslot[t];
    float2 w = wsel[t];
    const size_t PS = (size_t)MAXSLOTS * DIM;
    float ax = 0.f, ay = 0.f, az = 0.f, aw = 0.f;
    float bxs = 0.f, bys = 0.f, bzs = 0.f, bws = 0.f;
    #pragma unroll
    for (int p = 0; p < NP; ++p) {
        ushort4 a = *reinterpret_cast<const ushort4*>(accP + p * PS + (size_t)s.x * DIM + d4);
        ushort4 b = *reinterpret_cast<const ushort4*>(accP + p * PS + (size_t)s.y * DIM + d4);
        ax += bf2f(a.x); ay += bf2f(a.y); az += bf2f(a.z); aw += bf2f(a.w);
        bxs += bf2f(b.x); bys += bf2f(b.y); bzs += bf2f(b.z); bws += bf2f(b.w);
    }
    float4 o = *reinterpret_cast<const float4*>(xo + (size_t)t * DIM + d4);
    o.x += w.x * ax + w.y * bxs;
    o.y += w.x * ay + w.y * bys;
    o.z += w.x * az + w.y * bzs;
    o.w += w.x * aw + w.y * bws;
    *reinterpret_cast<float4*>(xo + (size_t)t * DIM + d4) = o;
}

extern "C" void kernel_launch(void* const* d_in, const int* in_sizes, int n_in,
                              void* d_out, int out_size, void* d_ws, size_t ws_size,
                              hipStream_t stream) {
    const float* x    = (const float*)d_in[0];
    const float* ln1w = (const float*)d_in[1];
    const float* ln2w = (const float*)d_in[2];
    const float* wq   = (const float*)d_in[3];
    const float* wk   = (const float*)d_in[4];
    const float* wv   = (const float*)d_in[5];
    const float* wo   = (const float*)d_in[6];
    const float* wr   = (const float*)d_in[7];
    const float* w1   = (const float*)d_in[8];
    const float* w2   = (const float*)d_in[9];
    float* xo = (float*)d_out;

    const size_t NTD = (size_t)TOKS * DIM;
    const size_t MB = 1024 * 1024;
    char* p = (char*)d_ws;

    // ---- persistent region ----
    u16* wqkvT = (u16*)p;                       // 6 MB
    u16* woT   = wqkvT + 3 * MB;                // 2 MB
    u16* h2b   = woT + MB;                      // 8 MB
    int* hdr      = (int*)(h2b + NTD);
    int* slot_tok = hdr + 128;
    float* slot_w = (float*)(slot_tok + MAXSLOTS);
    int* esel     = (int*)(slot_w + MAXSLOTS);
    float2* wsel  = (float2*)(esel + TOKS);
    int2* tslot   = (int2*)(wsel + TOKS);
    float* zz     = (float*)(tslot + TOKS);
    float* pp     = zz + TOKS;

    // ---- union region U ----
    char* U = (char*)(pp + TOKS * 8) + 256;
    u16* h_bf = (u16*)U;            // swz tile-major
    u16* qb   = h_bf + NTD;         // row-major
    u16* kb   = qb + NTD;
    u16* vb   = kb + NTD;
    u16* vt   = vb + NTD;
    u16* ctx  = vt + NTD;           // swz tile-major
    u16* woP  = (u16*)(U + 72 * MB);                        // [4][NTD] bf16 = 32 MB
    u16* he   = (u16*)U;                                    // 72 MB swz tile-major
    u16* hg   = (u16*)(U + 72 * MB);                        // 18 MB swz tile-major
    u16* w1T  = (u16*)(U + 90 * MB);                        // 64 MB swz tile-major
    u16* w2T  = w1T + (size_t)NEXP * FF * DIM;              // 64 MB
    u16* accP = w2T + (size_t)NEXP * DIM * FF;              // [4][MAXSLOTS][DIM] bf16 = 72 MB

    // 1) attention-path weight transposes
    tconv_k<<<dim3(16, 16), 256, 0, stream>>>(wq, wqkvT,          DIM, DIM);
    tconv_k<<<dim3(16, 16), 256, 0, stream>>>(wk, wqkvT + MB,     DIM, DIM);
    tconv_k<<<dim3(16, 16), 256, 0, stream>>>(wv, wqkvT + 2 * MB, DIM, DIM);
    tconv_k<<<dim3(16, 16), 256, 0, stream>>>(wo, woT,            DIM, DIM);

    // 2) h = rmsnorm(x)
    rmsnorm_k<0, 1, 0><<<TOKS, 256, 0, stream>>>(x, ln1w, h_bf, nullptr, nullptr,
                                                 nullptr, nullptr, nullptr, nullptr, nullptr);

    // 3) fused q,k,v
    mgemm<0, 24, 1, 4><<<dim3(24, TOKS / 128), 256, 0, stream>>>(
        h_bf, wqkvT, qb, kb, vb, nullptr, DIM, DIM, 0);

    // 4) V transpose + flash attention
    vtrans_k<<<dim3(SEQ / 64, NBATCH * NHEAD), 256, 0, stream>>>(vb, vt);
    fattn<<<NBATCH * NHEAD * (SEQ / 64), 256, 0, stream>>>(qb, kb, vt, ctx);

    // 5) wo split-K x4 (bf16 partials)
    mgemm<1, 8, 4, 2><<<dim3(8, (TOKS / 128) * 4), 256, 0, stream>>>(
        ctx, woT, woP, nullptr, nullptr, nullptr, DIM, DIM, NTD);

    // 6) h2 = rmsnorm(x + sum of 4 woP) + fused router; writes x1 to xo
    rmsnorm_k<1, 0, 4><<<TOKS, 256, 0, stream>>>(x, ln2w, h2b, wr, esel, wsel,
                                                 zz, pp, woP, xo);

    // 7) scheduler + router loss
    sched_k<<<1, 256, 0, stream>>>(esel, wsel, zz, pp, hdr, slot_tok, slot_w, tslot, xo + NTD);

    // 8) gather tokens to slot-major swz tile-major hg
    gather_k<<<MAXSLOTS / 4, 256, 0, stream>>>(h2b, slot_tok, hdr, hg);

    // 9) expert-weight transposes
    tconvE_k<<<16384, 256, 0, stream>>>(w1, w2, w1T, w2T);

    // 10) MoE up: he = gelu(hg @ w1[e])
    mgemm<2, 32, 1, 4><<<dim3(FF / 128, MAXTILES), 256, 0, stream>>>(
        hg, w1T, he, nullptr, nullptr, hdr, DIM, FF, 0);

    // 11) MoE down split-K x4 (bf16 partials; each XCD row owns one K-slice)
    mgemm<3, 8, 4, 2><<<dim3(8, MAXTILES * 4), 256, 0, stream>>>(
        he, w2T, accP, nullptr, nullptr, hdr, FF, DIM, (size_t)MAXSLOTS * DIM);

    // 12) combine expert outputs into xo (4 partials)
    combine_k<4><<<TOKS, 256, 0, stream>>>(accP, tslot, wsel, xo);
}

// Round 17
// 486.607 us; speedup vs baseline: 1.0792x; 1.0792x over previous
//
#include <hip/hip_runtime.h>
#include <hip/hip_bf16.h>
#include <math.h>
#include <stddef.h>
#include <stdint.h>

#define TOKS 4096
#define DIM  1024
#define FF   4096
#define NEXP 8
#define NHEAD 16
#define HDIM 64
#define SEQ  1024
#define NBATCH 4
#define MAXSLOTS 10240   // 8192 + 8*255 rounded to 256-multiples
#define MAXT256 40       // max 256-row tiles

// Swizzled tile-major layout for GEMM operands: logical [M][K] stored as
// [(r>>7)][(k>>6)] tiles of 8192 elems; elem (r,k) at
// ((r>>7)*(K>>6) + (k>>6))*8192 + (r&127)*64 + ((k&63) ^ ((r&7)<<3)).

typedef __attribute__((ext_vector_type(8))) short short8;   // 8 bf16
typedef __attribute__((ext_vector_type(4))) float f32x4;
typedef unsigned short u16;

__device__ __forceinline__ u16 f2bf(float f) {
    __hip_bfloat16 b = __float2bfloat16(f);
    return *reinterpret_cast<u16*>(&b);
}

__device__ __forceinline__ float bf2f(u16 u) {
    __hip_bfloat16 b = *reinterpret_cast<__hip_bfloat16*>(&u);
    return __bfloat162float(b);
}

__device__ __forceinline__ int tswz(int row, int col) {
    return col ^ ((row & 7) << 3);
}

__device__ __forceinline__ float gelu_fast(float x) {
    float s = x * x;
    float t = x * fmaf(s, 0.0713548162f, 1.5957691216f);
    float e = __expf(-t);
    return x * __builtin_amdgcn_rcpf(1.f + e);
}

// async global->LDS, 16 bytes/lane (LDS dest linear: base + lane*16)
__device__ __forceinline__ void gl2lds16(const void* g, void* l) {
    __builtin_amdgcn_global_load_lds((const __attribute__((address_space(1))) void*)g,
                                     (__attribute__((address_space(3))) void*)l,
                                     16, 0, 0);
}

// ---------------- RMSNorm (+ optional fused router, + optional fused residual-combine) ----------------
template <int ROUTER, int TM, int RES>
__global__ __launch_bounds__(256) void rmsnorm_k(const float* __restrict__ x,
                                                 const float* __restrict__ w,
                                                 u16* __restrict__ ob,
                                                 const float* __restrict__ wr,
                                                 int* __restrict__ esel,
                                                 float2* __restrict__ wsel,
                                                 float* __restrict__ zz,
                                                 float* __restrict__ pp,
                                                 const u16* __restrict__ resP,
                                                 float* __restrict__ xo_out) {
    int t = blockIdx.x, tid = threadIdx.x;
    float4 xv = reinterpret_cast<const float4*>(x + (size_t)t * DIM)[tid];
    if (RES) {
        const size_t NTD = (size_t)TOKS * DIM;
        size_t d4 = (size_t)t * DIM + tid * 4;
        #pragma unroll
        for (int ks = 0; ks < RES; ++ks) {
            ushort4 v = *reinterpret_cast<const ushort4*>(resP + ks * NTD + d4);
            xv.x += bf2f(v.x); xv.y += bf2f(v.y); xv.z += bf2f(v.z); xv.w += bf2f(v.w);
        }
        *reinterpret_cast<float4*>(xo_out + d4) = xv;
    }
    float ss = xv.x * xv.x + xv.y * xv.y + xv.z * xv.z + xv.w * xv.w;
    #pragma unroll
    for (int off = 32; off; off >>= 1) ss += __shfl_xor(ss, off);
    __shared__ float red[4];
    if ((tid & 63) == 0) red[tid >> 6] = ss;
    __syncthreads();
    float tot = red[0] + red[1] + red[2] + red[3];
    float scale = rsqrtf(tot * (1.0f / (float)DIM) + 1e-5f);
    float4 wv = reinterpret_cast<const float4*>(w)[tid];
    float4 ov;
    ov.x = xv.x * scale * wv.x;
    ov.y = xv.y * scale * wv.y;
    ov.z = xv.z * scale * wv.z;
    ov.w = xv.w * scale * wv.w;
    ushort4 pk;
    pk.x = f2bf(ov.x); pk.y = f2bf(ov.y); pk.z = f2bf(ov.z); pk.w = f2bf(ov.w);
    if (TM) {
        size_t addr = ((size_t)(t >> 7) * 16 + (tid >> 4)) * 8192 +
                      (size_t)(t & 127) * 64 + tswz(t, (tid * 4) & 63);
        *reinterpret_cast<ushort4*>(ob + addr) = pk;
    } else {
        *reinterpret_cast<ushort4*>(ob + (size_t)t * DIM + tid * 4) = pk;
    }

    if (ROUTER) {
        int d0 = tid * 4;
        const float* wp = wr + (size_t)d0 * NEXP;
        float pl[8];
        float4 a0 = *reinterpret_cast<const float4*>(wp + 0);
        float4 a1 = *reinterpret_cast<const float4*>(wp + 4);
        float4 b0 = *reinterpret_cast<const float4*>(wp + 8);
        float4 b1 = *reinterpret_cast<const float4*>(wp + 12);
        float4 c0 = *reinterpret_cast<const float4*>(wp + 16);
        float4 c1 = *reinterpret_cast<const float4*>(wp + 20);
        float4 d0v = *reinterpret_cast<const float4*>(wp + 24);
        float4 d1v = *reinterpret_cast<const float4*>(wp + 28);
        pl[0] = ov.x * a0.x + ov.y * b0.x + ov.z * c0.x + ov.w * d0v.x;
        pl[1] = ov.x * a0.y + ov.y * b0.y + ov.z * c0.y + ov.w * d0v.y;
        pl[2] = ov.x * a0.z + ov.y * b0.z + ov.z * c0.z + ov.w * d0v.z;
        pl[3] = ov.x * a0.w + ov.y * b0.w + ov.z * c0.w + ov.w * d0v.w;
        pl[4] = ov.x * a1.x + ov.y * b1.x + ov.z * c1.x + ov.w * d1v.x;
        pl[5] = ov.x * a1.y + ov.y * b1.y + ov.z * c1.y + ov.w * d1v.y;
        pl[6] = ov.x * a1.z + ov.y * b1.z + ov.z * c1.z + ov.w * d1v.z;
        pl[7] = ov.x * a1.w + ov.y * b1.w + ov.z * c1.w + ov.w * d1v.w;
        #pragma unroll
        for (int e = 0; e < 8; ++e) {
            #pragma unroll
            for (int off = 32; off; off >>= 1) pl[e] += __shfl_xor(pl[e], off);
        }
        __shared__ float red2[4][8];
        if ((tid & 63) == 0) {
            #pragma unroll
            for (int e = 0; e < 8; ++e) red2[tid >> 6][e] = pl[e];
        }
        __syncthreads();
        if (tid == 0) {
            float lg[8];
            #pragma unroll
            for (int e = 0; e < 8; ++e)
                lg[e] = red2[0][e] + red2[1][e] + red2[2][e] + red2[3][e];
            float mx = lg[0];
            #pragma unroll
            for (int e = 1; e < 8; ++e) mx = fmaxf(mx, lg[e]);
            float p[8], se = 0.f;
            #pragma unroll
            for (int e = 0; e < 8; ++e) { p[e] = __expf(lg[e] - mx); se += p[e]; }
            float inv = 1.f / se;
            #pragma unroll
            for (int e = 0; e < 8; ++e) p[e] *= inv;
            int i0 = 0;
            #pragma unroll
            for (int e = 1; e < 8; ++e) if (p[e] > p[i0]) i0 = e;
            int i1 = (i0 == 0) ? 1 : 0;
            #pragma unroll
            for (int e = 0; e < 8; ++e) if (e != i0 && p[e] > p[i1]) i1 = e;
            float w0 = p[i0], w1 = p[i1], s = w0 + w1;
            esel[t] = i0 | (i1 << 8);
            wsel[t] = make_float2(w0 / s, w1 / s);
            float z = mx + logf(se);
            zz[t] = z * z;
            #pragma unroll
            for (int e = 0; e < 8; ++e) pp[(size_t)t * 8 + e] = p[e];
        }
    }
}

// ---------------- tconv body: in[K][N] fp32 slab -> out swizzled tile-major [N][K] bf16 ----------------
__device__ __forceinline__ void tconv_body(const float* __restrict__ ip,
                                           u16* __restrict__ op,
                                           int K, int N, int r0, int c0, int t) {
    __shared__ float tile[64][65];
    #pragma unroll
    for (int i = 0; i < 4; ++i) {
        int r = (t >> 4) + i * 16;
        float4 v = *reinterpret_cast<const float4*>(&ip[(size_t)(r0 + r) * N + c0 + (t & 15) * 4]);
        tile[r][(t & 15) * 4 + 0] = v.x;
        tile[r][(t & 15) * 4 + 1] = v.y;
        tile[r][(t & 15) * 4 + 2] = v.z;
        tile[r][(t & 15) * 4 + 3] = v.w;
    }
    __syncthreads();
    int c = t >> 2, rr = (t & 3) * 16;
    short8 v0, v1;
    #pragma unroll
    for (int u = 0; u < 8; ++u) v0[u] = (short)f2bf(tile[rr + u][c]);
    #pragma unroll
    for (int u = 0; u < 8; ++u) v1[u] = (short)f2bf(tile[rr + 8 + u][c]);
    int n = c0 + c;
    int k = r0 + rr;
    size_t tb = ((size_t)(n >> 7) * (K >> 6) + (k >> 6)) * 8192 + (size_t)(n & 127) * 64;
    *reinterpret_cast<short8*>(&op[tb + tswz(n, k & 63)]) = v0;
    *reinterpret_cast<short8*>(&op[tb + tswz(n, (k + 8) & 63)]) = v1;
}

__global__ __launch_bounds__(256) void tconv_k(const float* __restrict__ in,
                                               u16* __restrict__ out,
                                               int K, int N) {
    tconv_body(in, out, K, N, blockIdx.y * 64, blockIdx.x * 64, threadIdx.x);
}

__global__ __launch_bounds__(256) void tconvE_k(const float* __restrict__ w1,
                                                const float* __restrict__ w2,
                                                u16* __restrict__ w1T,
                                                u16* __restrict__ w2T) {
    int bid = blockIdx.x;
    int half = bid >> 13;
    int eb = bid & 8191;
    int e = eb >> 10;
    int t = eb & 1023;
    const size_t ED = (size_t)DIM * FF;
    if (half == 0) {
        int bxx = t & 63, byy = t >> 6;
        tconv_body(w1 + (size_t)e * ED, w1T + (size_t)e * ED,
                   DIM, FF, byy * 64, bxx * 64, threadIdx.x);
    } else {
        int bxx = t & 15, byy = t >> 4;
        tconv_body(w2 + (size_t)e * ED, w2T + (size_t)e * ED,
                   FF, DIM, byy * 64, bxx * 64, threadIdx.x);
    }
}

// ---------------- V transpose per head: vb[B*S][D] bf16 -> vt[BH][64][S] ----------------
__global__ __launch_bounds__(256) void vtrans_k(const u16* __restrict__ vb,
                                                u16* __restrict__ vt) {
    __shared__ u16 tile[64][80];
    int bh = blockIdx.y;
    int b = bh >> 4, h = bh & 15;
    int s0 = blockIdx.x * 64;
    int t = threadIdx.x;
    #pragma unroll
    for (int i = 0; i < 2; ++i) {
        int chunk = i * 256 + t;
        int r = chunk >> 3;
        int c = (chunk & 7) * 8;
        short8 v = *reinterpret_cast<const short8*>(
            &vb[(size_t)(b * SEQ + s0 + r) * DIM + h * HDIM + c]);
        *reinterpret_cast<short8*>(&tile[r][c]) = v;
    }
    __syncthreads();
    int d = t >> 2, s16 = (t & 3) * 16;
    short8 o0, o1;
    #pragma unroll
    for (int u = 0; u < 8; ++u) o0[u] = (short)tile[s16 + u][d];
    #pragma unroll
    for (int u = 0; u < 8; ++u) o1[u] = (short)tile[s16 + 8 + u][d];
    size_t ob = ((size_t)bh * HDIM + d) * SEQ + s0 + s16;
    *reinterpret_cast<short8*>(&vt[ob]) = o0;
    *reinterpret_cast<short8*>(&vt[ob + 8]) = o1;
}

// ---------------- Gather: hg[slot] = h2b[slot_tok[slot]] in swizzled tile-major ----------------
__global__ __launch_bounds__(256) void gather_k(const u16* __restrict__ h2b,
                                                const int* __restrict__ slot_tok,
                                                const int* __restrict__ hdr,
                                                u16* __restrict__ hg) {
    int s = blockIdx.x * 4 + (threadIdx.x >> 6);
    if (s >= (hdr[0] << 8)) return;       // hdr[0] counts 256-row tiles
    int lane = threadIdx.x & 63;
    int tok = slot_tok[s];
    const short8* src = reinterpret_cast<const short8*>(h2b + (size_t)tok * DIM + lane * 16);
    size_t tb = ((size_t)(s >> 7) * 16 + (lane >> 2)) * 8192 + (size_t)(s & 127) * 64;
    int col = (lane * 16) & 63;
    short8 v0 = src[0], v1 = src[1];
    *reinterpret_cast<short8*>(hg + tb + tswz(s, col)) = v0;
    *reinterpret_cast<short8*>(hg + tb + tswz(s, col + 8)) = v1;
}

// ---------------- MFMA GEMM 128x128 (round-15 structure): QKV + wo ----------------
// MODE 0: fused QKV (Bt=concat wqT,wkT,wvT; sel=bx>>3 -> C0/C1/C2 bf16 row-major)
// MODE 1: C0(bf16 partial[ks]) = A@B slice            (wo)
template <int MODE, int GX, int SPLITK, int PX>
__global__ __launch_bounds__(256) void mgemm(const u16* __restrict__ A,
                                             const u16* __restrict__ Bt,
                                             void* __restrict__ C0,
                                             void* __restrict__ C1,
                                             void* __restrict__ C2,
                                             int K, int N, size_t part_stride) {
    __shared__ __align__(16) u16 As[128 * 64];
    __shared__ __align__(16) u16 Bs[128 * 64];
    const int tid = threadIdx.x;
    const int lane = tid & 63;
    const int w = tid >> 6;
    const int wr = w >> 1, wc = w & 1;
    const int lo = lane & 15, hi = lane >> 4;

    const int PY = 8 / PX;
    const int LBX = GX / PX;
    const int LBY = (int)gridDim.y / PY;
    int f = (int)blockIdx.y * GX + (int)blockIdx.x;
    int xcd = f & 7;
    int j = f >> 3;
    int cx = xcd % PX, cy = xcd / PX;
    int lbx = j % LBX, lby = j / LBX;
    const int bx = cx * LBX + lbx;
    const int by_raw = cy * LBY + lby;
    const int TY = (int)gridDim.y / SPLITK;
    const int ksid = by_raw / TY;
    const int by = by_raw % TY;

    const u16* Bbase = Bt + (size_t)bx * 128 * K;
    const size_t row0 = (size_t)by * 128;
    const u16* Abase = A + row0 * K;

    f32x4 acc[4][4];
    #pragma unroll
    for (int m = 0; m < 4; ++m)
        #pragma unroll
        for (int n = 0; n < 4; ++n) acc[m][n] = (f32x4){0.f, 0.f, 0.f, 0.f};

    const int KS = K / SPLITK;
    const int kb = ksid * KS;
    for (int k0 = kb; k0 < kb + KS; k0 += 64) {
        const u16* at = Abase + (size_t)k0 * 128;
        const u16* bt = Bbase + (size_t)k0 * 128;
        #pragma unroll
        for (int i = 0; i < 4; ++i) {
            int chunk = i * 256 + tid;
            gl2lds16(at + chunk * 8, &As[chunk * 8]);
        }
        #pragma unroll
        for (int i = 0; i < 4; ++i) {
            int chunk = i * 256 + tid;
            gl2lds16(bt + chunk * 8, &Bs[chunk * 8]);
        }
        __syncthreads();
        #pragma unroll
        for (int ks = 0; ks < 2; ++ks) {
            short8 a[4], b[4];
            #pragma unroll
            for (int m = 0; m < 4; ++m) {
                int row = wr * 64 + m * 16 + lo;
                a[m] = *reinterpret_cast<const short8*>(
                    &As[row * 64 + tswz(row, ks * 32 + hi * 8)]);
            }
            #pragma unroll
            for (int n = 0; n < 4; ++n) {
                int row = wc * 64 + n * 16 + lo;
                b[n] = *reinterpret_cast<const short8*>(
                    &Bs[row * 64 + tswz(row, ks * 32 + hi * 8)]);
            }
            #pragma unroll
            for (int m = 0; m < 4; ++m)
                #pragma unroll
                for (int n = 0; n < 4; ++n)
                    acc[m][n] = __builtin_amdgcn_mfma_f32_16x16x32_bf16(a[m], b[n], acc[m][n], 0, 0, 0);
        }
        __syncthreads();
    }

    u16* Pf = (u16*)C0 + (size_t)ksid * part_stride;
    #pragma unroll
    for (int m = 0; m < 4; ++m) {
        #pragma unroll
        for (int j2 = 0; j2 < 4; ++j2) {
            int rloc = wr * 64 + m * 16 + hi * 4 + j2;
            size_t r = row0 + rloc;
            #pragma unroll
            for (int n = 0; n < 4; ++n) {
                float v = acc[m][n][j2];
                if (MODE == 0) {
                    int sel = bx >> 3;
                    size_t ccl = (size_t)((bx & 7) * 128 + wc * 64 + n * 16 + lo);
                    u16* Cp = (sel == 0) ? (u16*)C0 : (sel == 1) ? (u16*)C1 : (u16*)C2;
                    Cp[r * N + ccl] = f2bf(v);
                } else {
                    size_t cc = (size_t)(bx * 128 + wc * 64 + n * 16 + lo);
                    Pf[r * N + cc] = f2bf(v);
                }
            }
        }
    }
}

// ---------------- MFMA GEMM2 256x128 (8 waves, 48KB LDS, single-buffer 2-phase): MoE up/down ----------------
// MODE 2: C0(bf16 swz tile-major) = gelu(A@B); A = hg; Bt = w1T[e]
// MODE 3: C0(bf16 partial[ks] row-major) = A@B slice; A = he; Bt = w2T[e]
// Expert lists are 256-padded, so a 256-row block never straddles experts.
template <int MODE, int GX, int SPLITK, int PX>
__global__ __launch_bounds__(512) void mgemm2(const u16* __restrict__ A,
                                              const u16* __restrict__ Bt,
                                              void* __restrict__ C0,
                                              const int* __restrict__ hdr,
                                              int K, int N, size_t part_stride) {
    __shared__ __align__(16) u16 As[256 * 64];   // 32 KB (two 128-row subtiles stacked)
    __shared__ __align__(16) u16 Bs[128 * 64];   // 16 KB
    const int tid = threadIdx.x;
    const int lane = tid & 63;
    const int w = tid >> 6;          // 0..7
    const int wr = w >> 1;           // 0..3: M quadrant (64 rows)
    const int wc = w & 1;            // 0..1: N half (64 cols)
    const int lo = lane & 15, hi = lane >> 4;

    const int PY = 8 / PX;
    const int LBX = GX / PX;
    const int LBY = (int)gridDim.y / PY;
    int f = (int)blockIdx.y * GX + (int)blockIdx.x;
    int xcd = f & 7;
    int j = f >> 3;
    int cx = xcd % PX, cy = xcd / PX;
    int lbx = j % LBX, lby = j / LBX;
    const int bx = cx * LBX + lbx;
    const int by_raw = cy * LBY + lby;
    const int TY = (int)gridDim.y / SPLITK;
    const int ksid = by_raw / TY;
    const int by = by_raw % TY;      // 256-row tile index

    if (by >= hdr[0]) return;
    int e = hdr[1 + by];
    const u16* Bbase = Bt + (size_t)e * N * K + (size_t)bx * 128 * K;
    const size_t row0 = (size_t)by * 256;
    const size_t tstride = (size_t)(K >> 6) * 8192;   // elems per 128-row tile
    const u16* Abase = A + (size_t)(by * 2) * tstride;

    f32x4 acc[4][4];
    #pragma unroll
    for (int m = 0; m < 4; ++m)
        #pragma unroll
        for (int n = 0; n < 4; ++n) acc[m][n] = (f32x4){0.f, 0.f, 0.f, 0.f};

    const int KS = K / SPLITK;
    const int kb = ksid * KS;
    for (int k0 = kb; k0 < kb + KS; k0 += 64) {
        const u16* at0 = Abase + (size_t)k0 * 128;
        const u16* at1 = at0 + tstride;
        const u16* bt = Bbase + (size_t)k0 * 128;
        #pragma unroll
        for (int i = 0; i < 2; ++i) {
            int c = i * 512 + tid;
            gl2lds16(at0 + c * 8, &As[c * 8]);
        }
        #pragma unroll
        for (int i = 0; i < 2; ++i) {
            int c = i * 512 + tid;
            gl2lds16(at1 + c * 8, &As[8192 + c * 8]);
        }
        #pragma unroll
        for (int i = 0; i < 2; ++i) {
            int c = i * 512 + tid;
            gl2lds16(bt + c * 8, &Bs[c * 8]);
        }
        __syncthreads();
        #pragma unroll
        for (int ks = 0; ks < 2; ++ks) {
            short8 a[4], b[4];
            #pragma unroll
            for (int m = 0; m < 4; ++m) {
                int row = wr * 64 + m * 16 + lo;                 // 0..255
                a[m] = *reinterpret_cast<const short8*>(
                    &As[(row >> 7) * 8192 + (row & 127) * 64 + tswz(row, ks * 32 + hi * 8)]);
            }
            #pragma unroll
            for (int n = 0; n < 4; ++n) {
                int row = wc * 64 + n * 16 + lo;                 // 0..127
                b[n] = *reinterpret_cast<const short8*>(
                    &Bs[row * 64 + tswz(row, ks * 32 + hi * 8)]);
            }
            #pragma unroll
            for (int m = 0; m < 4; ++m)
                #pragma unroll
                for (int n = 0; n < 4; ++n)
                    acc[m][n] = __builtin_amdgcn_mfma_f32_16x16x32_bf16(a[m], b[n], acc[m][n], 0, 0, 0);
        }
        __syncthreads();
    }

    u16* Pf = (u16*)C0 + (size_t)ksid * part_stride;
    #pragma unroll
    for (int m = 0; m < 4; ++m) {
        #pragma unroll
        for (int j2 = 0; j2 < 4; ++j2) {
            int rloc = wr * 64 + m * 16 + hi * 4 + j2;           // 0..255
            size_t r = row0 + rloc;
            #pragma unroll
            for (int n = 0; n < 4; ++n) {
                float v = acc[m][n][j2];
                if (MODE == 2) {
                    size_t tile = (size_t)(by * 2 + (rloc >> 7)) * (N >> 6) + (size_t)bx * 2 + wc;
                    ((u16*)C0)[tile * 8192 + (size_t)(rloc & 127) * 64 + tswz(rloc, n * 16 + lo)] =
                        f2bf(gelu_fast(v));
                } else {
                    size_t cc = (size_t)(bx * 128 + wc * 64 + n * 16 + lo);
                    Pf[r * N + cc] = f2bf(v);
                }
            }
        }
    }
}

// ---------------- Flash attention (LDS-staged K/V, online softmax, swz ctx out) ----------------
__global__ __launch_bounds__(256) void fattn(const u16* __restrict__ Q,
                                             const u16* __restrict__ Kb,
                                             const u16* __restrict__ Vt,
                                             u16* __restrict__ O) {
    __shared__ __align__(16) char Ks[64 * 128];
    __shared__ __align__(16) char Vs[64 * 128];
    __shared__ __align__(16) char Ps[4][16 * 128];
    const int tid = threadIdx.x, lane = tid & 63, w = tid >> 6;
    const int lo = lane & 15, hi = lane >> 4;
    int fb = (int)blockIdx.x;
    fb = (fb & 7) * ((NBATCH * NHEAD * (SEQ / 64)) >> 3) + (fb >> 3);
    const int qt = fb & 15;
    const int bh = fb >> 4;
    const int b = bh >> 4, h = bh & 15;

    size_t qtok = (size_t)(b * SEQ + qt * 64 + w * 16 + lo);
    short8 qf[2];
    #pragma unroll
    for (int ks = 0; ks < 2; ++ks)
        qf[ks] = *reinterpret_cast<const short8*>(&Q[qtok * DIM + h * HDIM + ks * 32 + hi * 8]);

    float m_r[4], l_r[4];
    f32x4 oa[4];
    #pragma unroll
    for (int j = 0; j < 4; ++j) { m_r[j] = -1e30f; l_r[j] = 0.f; }
    #pragma unroll
    for (int n = 0; n < 4; ++n) oa[n] = (f32x4){0.f, 0.f, 0.f, 0.f};

    const size_t kbase = ((size_t)b * SEQ) * DIM + h * HDIM;
    const size_t vbase = ((size_t)bh * HDIM) * SEQ;
    char* P = Ps[w];

    for (int kt = 0; kt < 16; ++kt) {
        __syncthreads();
        #pragma unroll
        for (int i = 0; i < 2; ++i) {
            int chunk = i * 256 + tid;
            int r = chunk >> 3;
            int cb = (chunk & 7) << 4;
            short8 v = *reinterpret_cast<const short8*>(
                &Kb[kbase + (size_t)(kt * 64 + r) * DIM + (cb >> 1)]);
            *reinterpret_cast<short8*>(&Ks[r * 128 + (cb ^ ((r & 7) << 4))]) = v;
        }
        #pragma unroll
        for (int i = 0; i < 2; ++i) {
            int chunk = i * 256 + tid;
            int r = chunk >> 3;
            int cb = (chunk & 7) << 4;
            short8 v = *reinterpret_cast<const short8*>(
                &Vt[vbase + (size_t)r * SEQ + kt * 64 + (cb >> 1)]);
            *reinterpret_cast<short8*>(&Vs[r * 128 + (cb ^ ((r & 7) << 4))]) = v;
        }
        __syncthreads();

        f32x4 s[4];
        #pragma unroll
        for (int n = 0; n < 4; ++n) {
            f32x4 z = {0.f, 0.f, 0.f, 0.f};
            #pragma unroll
            for (int ks = 0; ks < 2; ++ks) {
                int row = n * 16 + lo;
                int cb = (ks * 32 + hi * 8) * 2;
                short8 kf = *reinterpret_cast<const short8*>(
                    &Ks[row * 128 + (cb ^ ((row & 7) << 4))]);
                z = __builtin_amdgcn_mfma_f32_16x16x32_bf16(qf[ks], kf, z, 0, 0, 0);
            }
            s[n] = z * 0.125f;
        }

        float mx[4];
        #pragma unroll
        for (int j = 0; j < 4; ++j) {
            mx[j] = fmaxf(fmaxf(s[0][j], s[1][j]), fmaxf(s[2][j], s[3][j]));
            #pragma unroll
            for (int off = 1; off < 16; off <<= 1) mx[j] = fmaxf(mx[j], __shfl_xor(mx[j], off));
        }
        float corr[4], rsum[4];
        #pragma unroll
        for (int j = 0; j < 4; ++j) {
            float mn = fmaxf(m_r[j], mx[j]);
            corr[j] = __expf(m_r[j] - mn);
            m_r[j] = mn;
            rsum[j] = 0.f;
        }
        #pragma unroll
        for (int n = 0; n < 4; ++n)
            #pragma unroll
            for (int j = 0; j < 4; ++j) {
                float p = __expf(s[n][j] - m_r[j]);
                s[n][j] = p;
                rsum[j] += p;
            }
        #pragma unroll
        for (int j = 0; j < 4; ++j) {
            #pragma unroll
            for (int off = 1; off < 16; off <<= 1) rsum[j] += __shfl_xor(rsum[j], off);
            l_r[j] = l_r[j] * corr[j] + rsum[j];
        }
        #pragma unroll
        for (int n = 0; n < 4; ++n)
            #pragma unroll
            for (int j = 0; j < 4; ++j) oa[n][j] *= corr[j];

        #pragma unroll
        for (int n = 0; n < 4; ++n)
            #pragma unroll
            for (int j = 0; j < 4; ++j) {
                int q = hi * 4 + j;
                int key = n * 16 + lo;
                *reinterpret_cast<u16*>(&P[q * 128 + ((key * 2) ^ ((q & 7) << 4))]) =
                    f2bf(s[n][j]);
            }

        #pragma unroll
        for (int ks = 0; ks < 2; ++ks) {
            int keyb = (ks * 32 + hi * 8) * 2;
            short8 pf = *reinterpret_cast<const short8*>(
                &P[lo * 128 + (keyb ^ ((lo & 7) << 4))]);
            #pragma unroll
            for (int n = 0; n < 4; ++n) {
                int d = n * 16 + lo;
                short8 vf = *reinterpret_cast<const short8*>(
                    &Vs[d * 128 + (keyb ^ ((d & 7) << 4))]);
                oa[n] = __builtin_amdgcn_mfma_f32_16x16x32_bf16(pf, vf, oa[n], 0, 0, 0);
            }
        }
    }

    #pragma unroll
    for (int j = 0; j < 4; ++j) l_r[j] = 1.f / l_r[j];
    int otok = b * SEQ + qt * 64 + w * 16;
    #pragma unroll
    for (int n = 0; n < 4; ++n)
        #pragma unroll
        for (int j = 0; j < 4; ++j) {
            int r = otok + hi * 4 + j;
            size_t addr = ((size_t)(r >> 7) * 16 + h) * 8192 +
                          (size_t)(r & 127) * 64 + tswz(r, n * 16 + lo);
            O[addr] = f2bf(oa[n][j] * l_r[j]);
        }
}

// ---------------- Scheduler + loss (expert lists padded to 256) ----------------
__global__ __launch_bounds__(256) void sched_k(const int* __restrict__ esel,
                                               const float2* __restrict__ wsel,
                                               const float* __restrict__ zz,
                                               const float* __restrict__ pp,
                                               int* __restrict__ hdr,
                                               int* __restrict__ slot_tok,
                                               float* __restrict__ slot_w,
                                               int2* __restrict__ tslot,
                                               float* __restrict__ loss_out) {
    __shared__ int cnt[8], base[8], cur[8], tot_s;
    __shared__ float lred[4][9];
    int tid = threadIdx.x;
    if (tid < 8) { cnt[tid] = 0; cur[tid] = 0; }
    __syncthreads();
    for (int t = tid; t < TOKS; t += 256) {
        int es = esel[t];
        atomicAdd(&cnt[es & 255], 1);
        atomicAdd(&cnt[(es >> 8) & 255], 1);
    }
    __syncthreads();
    if (tid == 0) {
        int run = 0;
        for (int e = 0; e < 8; ++e) {
            base[e] = run;
            run += (cnt[e] + 255) & ~255;
        }
        tot_s = run;
        hdr[0] = run >> 8;     // number of 256-row tiles
    }
    __syncthreads();
    int ntiles = tot_s >> 8;
    for (int T = tid; T < ntiles; T += 256) {
        int r = T << 8;
        int e = 0;
        for (int k = 1; k < 8; ++k) if (r >= base[k]) e = k;
        hdr[1 + T] = e;
    }
    for (int t = tid; t < TOKS; t += 256) {
        int es = esel[t];
        float2 ww = wsel[t];
        int e0 = es & 255, e1 = (es >> 8) & 255;
        int s0 = base[e0] + atomicAdd(&cur[e0], 1);
        slot_tok[s0] = t; slot_w[s0] = ww.x;
        int s1 = base[e1] + atomicAdd(&cur[e1], 1);
        slot_tok[s1] = t; slot_w[s1] = ww.y;
        tslot[t] = make_int2(s0, s1);
    }
    __syncthreads();
    for (int idx = tid; idx < 8 * 256; idx += 256) {
        int e = idx >> 8, p2 = idx & 255;
        int c = cnt[e];
        int al = (c + 255) & ~255;
        if (c + p2 < al) {
            int s = base[e] + c + p2;
            slot_tok[s] = 0;
            slot_w[s] = 0.f;
        }
    }
    // router loss
    float sz = 0.f, sp[8] = {0, 0, 0, 0, 0, 0, 0, 0};
    for (int t = tid; t < TOKS; t += 256) {
        sz += zz[t];
        #pragma unroll
        for (int e = 0; e < 8; ++e) sp[e] += pp[(size_t)t * 8 + e];
    }
    #pragma unroll
    for (int off = 32; off; off >>= 1) {
        sz += __shfl_xor(sz, off);
        #pragma unroll
        for (int e = 0; e < 8; ++e) sp[e] += __shfl_xor(sp[e], off);
    }
    if ((tid & 63) == 0) {
        lred[tid >> 6][0] = sz;
        #pragma unroll
        for (int e = 0; e < 8; ++e) lred[tid >> 6][1 + e] = sp[e];
    }
    __syncthreads();
    if (tid == 0) {
        float tz = lred[0][0] + lred[1][0] + lred[2][0] + lred[3][0];
        float loss = 0.001f * (tz / (float)TOKS);
        float s = 0.f;
        for (int e = 0; e < 8; ++e) {
            float mp = (lred[0][1 + e] + lred[1][1 + e] + lred[2][1 + e] + lred[3][1 + e]) / (float)TOKS;
            s += mp * ((float)cnt[e] / (float)TOKS);
        }
        loss_out[0] = loss + (float)NEXP * s;
    }
}

// ---------------- Combine MoE: xo[tok] += sum over NP bf16 K-partials, 2 slots ----------------
template <int NP>
__global__ __launch_bounds__(256) void combine_k(const u16* __restrict__ accP,
                                                 const int2* __restrict__ tslot,
                                                 const float2* __restrict__ wsel,
                                                 float* __restrict__ xo) {
    int t = blockIdx.x;
    int d4 = threadIdx.x * 4;
    int2 s = tslot[t];
    float2 w = wsel[t];
    const size_t PS = (size_t)MAXSLOTS * DIM;
    float ax = 0.f, ay = 0.f, az = 0.f, aw = 0.f;
    float bxs = 0.f, bys = 0.f, bzs = 0.f, bws = 0.f;
    #pragma unroll
    for (int p = 0; p < NP; ++p) {
        ushort4 a = *reinterpret_cast<const ushort4*>(accP + p * PS + (size_t)s.x * DIM + d4);
        ushort4 b = *reinterpret_cast<const ushort4*>(accP + p * PS + (size_t)s.y * DIM + d4);
        ax += bf2f(a.x); ay += bf2f(a.y); az += bf2f(a.z); aw += bf2f(a.w);
        bxs += bf2f(b.x); bys += bf2f(b.y); bzs += bf2f(b.z); bws += bf2f(b.w);
    }
    float4 o = *reinterpret_cast<const float4*>(xo + (size_t)t * DIM + d4);
    o.x += w.x * ax + w.y * bxs;
    o.y += w.x * ay + w.y * bys;
    o.z += w.x * az + w.y * bzs;
    o.w += w.x * aw + w.y * bws;
    *reinterpret_cast<float4*>(xo + (size_t)t * DIM + d4) = o;
}

extern "C" void kernel_launch(void* const* d_in, const int* in_sizes, int n_in,
                              void* d_out, int out_size, void* d_ws, size_t ws_size,
                              hipStream_t stream) {
    const float* x    = (const float*)d_in[0];
    const float* ln1w = (const float*)d_in[1];
    const float* ln2w = (const float*)d_in[2];
    const float* wq   = (const float*)d_in[3];
    const float* wk   = (const float*)d_in[4];
    const float* wv   = (const float*)d_in[5];
    const float* wo   = (const float*)d_in[6];
    const float* wr   = (const float*)d_in[7];
    const float* w1   = (const float*)d_in[8];
    const float* w2   = (const float*)d_in[9];
    float* xo = (float*)d_out;

    const size_t NTD = (size_t)TOKS * DIM;
    const size_t MB = 1024 * 1024;
    char* p = (char*)d_ws;

    // ---- persistent region ----
    u16* wqkvT = (u16*)p;                       // 6 MB
    u16* woT   = wqkvT + 3 * MB;                // 2 MB
    u16* h2b   = woT + MB;                      // 8 MB
    int* hdr      = (int*)(h2b + NTD);
    int* slot_tok = hdr + 128;
    float* slot_w = (float*)(slot_tok + MAXSLOTS);
    int* esel     = (int*)(slot_w + MAXSLOTS);
    float2* wsel  = (float2*)(esel + TOKS);
    int2* tslot   = (int2*)(wsel + TOKS);
    float* zz     = (float*)(tslot + TOKS);
    float* pp     = zz + TOKS;

    // ---- union region U ----
    char* U = (char*)(pp + TOKS * 8) + 256;
    // attn phase (first 48 MB):
    u16* h_bf = (u16*)U;            // swz tile-major
    u16* qb   = h_bf + NTD;         // row-major
    u16* kb   = qb + NTD;
    u16* vb   = kb + NTD;
    u16* vt   = vb + NTD;
    u16* ctx  = vt + NTD;           // swz tile-major
    // MoE phase:
    u16* he   = (u16*)U;                                    // [10240][4096] bf16 = 80 MB
    u16* hg   = (u16*)(U + 80 * MB);                        // 20 MB swz tile-major
    u16* w1T  = (u16*)(U + 100 * MB);                       // 64 MB swz tile-major
    u16* w2T  = w1T + (size_t)NEXP * FF * DIM;              // 64 MB (U+164..228)
    u16* accP = w2T + (size_t)NEXP * DIM * FF;              // [2][10240][1024] bf16 = 40 MB (U+228..268)
    // wo partials live in the accP region during the attn phase (dead before step 11)
    u16* woP  = accP;                                       // [4][NTD] bf16 = 32 MB

    // 1) attention-path weight transposes
    tconv_k<<<dim3(16, 16), 256, 0, stream>>>(wq, wqkvT,          DIM, DIM);
    tconv_k<<<dim3(16, 16), 256, 0, stream>>>(wk, wqkvT + MB,     DIM, DIM);
    tconv_k<<<dim3(16, 16), 256, 0, stream>>>(wv, wqkvT + 2 * MB, DIM, DIM);
    tconv_k<<<dim3(16, 16), 256, 0, stream>>>(wo, woT,            DIM, DIM);

    // 2) h = rmsnorm(x)
    rmsnorm_k<0, 1, 0><<<TOKS, 256, 0, stream>>>(x, ln1w, h_bf, nullptr, nullptr,
                                                 nullptr, nullptr, nullptr, nullptr, nullptr);

    // 3) fused q,k,v
    mgemm<0, 24, 1, 4><<<dim3(24, TOKS / 128), 256, 0, stream>>>(
        h_bf, wqkvT, qb, kb, vb, DIM, DIM, 0);

    // 4) V transpose + flash attention
    vtrans_k<<<dim3(SEQ / 64, NBATCH * NHEAD), 256, 0, stream>>>(vb, vt);
    fattn<<<NBATCH * NHEAD * (SEQ / 64), 256, 0, stream>>>(qb, kb, vt, ctx);

    // 5) wo split-K x4 (bf16 partials)
    mgemm<1, 8, 4, 2><<<dim3(8, (TOKS / 128) * 4), 256, 0, stream>>>(
        ctx, woT, woP, nullptr, nullptr, DIM, DIM, NTD);

    // 6) h2 = rmsnorm(x + sum of 4 woP) + fused router; writes x1 to xo
    rmsnorm_k<1, 0, 4><<<TOKS, 256, 0, stream>>>(x, ln2w, h2b, wr, esel, wsel,
                                                 zz, pp, woP, xo);

    // 7) scheduler + router loss (256-padded expert lists)
    sched_k<<<1, 256, 0, stream>>>(esel, wsel, zz, pp, hdr, slot_tok, slot_w, tslot, xo + NTD);

    // 8) gather tokens to slot-major swz tile-major hg
    gather_k<<<MAXSLOTS / 4, 256, 0, stream>>>(h2b, slot_tok, hdr, hg);

    // 9) expert-weight transposes
    tconvE_k<<<16384, 256, 0, stream>>>(w1, w2, w1T, w2T);

    // 10) MoE up: he = gelu(hg @ w1[e])  (256x128 tile, 8 waves)
    mgemm2<2, 32, 1, 4><<<dim3(32, MAXT256), 512, 0, stream>>>(
        hg, w1T, he, hdr, DIM, FF, 0);

    // 11) MoE down split-K x2 (256x128 tile): accP[ks] = he @ w2 slice
    mgemm2<3, 8, 2, 2><<<dim3(8, MAXT256 * 2), 512, 0, stream>>>(
        he, w2T, accP, hdr, FF, DIM, (size_t)MAXSLOTS * DIM);

    // 12) combine expert outputs into xo (2 partials)
    combine_k<2><<<TOKS, 256, 0, stream>>>(accP, tslot, wsel, xo);
}

// Round 18
// 460.795 us; speedup vs baseline: 1.1396x; 1.0560x over previous
//
#include <hip/hip_runtime.h>
#include <hip/hip_bf16.h>
#include <math.h>
#include <stddef.h>
#include <stdint.h>

#define TOKS 4096
#define DIM  1024
#define FF   4096
#define NEXP 8
#define NHEAD 16
#define HDIM 64
#define SEQ  1024
#define NBATCH 4
#define MAXSLOTS 9216
#define MAXTILES 72

// Swizzled tile-major layout for GEMM operands: logical [M][K] stored as
// [(r>>7)][(k>>6)] tiles of 8192 elems; elem (r,k) at
// ((r>>7)*(K>>6) + (k>>6))*8192 + (r&127)*64 + ((k&63) ^ ((r&7)<<3)).

typedef __attribute__((ext_vector_type(8))) short short8;   // 8 bf16
typedef __attribute__((ext_vector_type(4))) float f32x4;
typedef unsigned short u16;

__device__ __forceinline__ u16 f2bf(float f) {
    __hip_bfloat16 b = __float2bfloat16(f);
    return *reinterpret_cast<u16*>(&b);
}

__device__ __forceinline__ float bf2f(u16 u) {
    __hip_bfloat16 b = *reinterpret_cast<__hip_bfloat16*>(&u);
    return __bfloat162float(b);
}

__device__ __forceinline__ int tswz(int row, int col) {
    return col ^ ((row & 7) << 3);
}

__device__ __forceinline__ float gelu_fast(float x) {
    float s = x * x;
    float t = x * fmaf(s, 0.0713548162f, 1.5957691216f);
    float e = __expf(-t);
    return x * __builtin_amdgcn_rcpf(1.f + e);
}

// async global->LDS, 16 bytes/lane (LDS dest linear: base + lane*16)
__device__ __forceinline__ void gl2lds16(const void* g, void* l) {
    __builtin_amdgcn_global_load_lds((const __attribute__((address_space(1))) void*)g,
                                     (__attribute__((address_space(3))) void*)l,
                                     16, 0, 0);
}

// ---------------- RMSNorm (+ optional fused router, + optional fused residual-combine) ----------------
// RES = number of bf16 residual partials to sum in (0 or 4).
template <int ROUTER, int TM, int RES>
__global__ __launch_bounds__(256) void rmsnorm_k(const float* __restrict__ x,
                                                 const float* __restrict__ w,
                                                 u16* __restrict__ ob,
                                                 const float* __restrict__ wr,
                                                 int* __restrict__ esel,
                                                 float2* __restrict__ wsel,
                                                 float* __restrict__ zz,
                                                 float* __restrict__ pp,
                                                 const u16* __restrict__ resP,
                                                 float* __restrict__ xo_out) {
    int t = blockIdx.x, tid = threadIdx.x;
    float4 xv = reinterpret_cast<const float4*>(x + (size_t)t * DIM)[tid];
    if (RES) {
        const size_t NTD = (size_t)TOKS * DIM;
        size_t d4 = (size_t)t * DIM + tid * 4;
        #pragma unroll
        for (int ks = 0; ks < RES; ++ks) {
            ushort4 v = *reinterpret_cast<const ushort4*>(resP + ks * NTD + d4);
            xv.x += bf2f(v.x); xv.y += bf2f(v.y); xv.z += bf2f(v.z); xv.w += bf2f(v.w);
        }
        *reinterpret_cast<float4*>(xo_out + d4) = xv;
    }
    float ss = xv.x * xv.x + xv.y * xv.y + xv.z * xv.z + xv.w * xv.w;
    #pragma unroll
    for (int off = 32; off; off >>= 1) ss += __shfl_xor(ss, off);
    __shared__ float red[4];
    if ((tid & 63) == 0) red[tid >> 6] = ss;
    __syncthreads();
    float tot = red[0] + red[1] + red[2] + red[3];
    float scale = rsqrtf(tot * (1.0f / (float)DIM) + 1e-5f);
    float4 wv = reinterpret_cast<const float4*>(w)[tid];
    float4 ov;
    ov.x = xv.x * scale * wv.x;
    ov.y = xv.y * scale * wv.y;
    ov.z = xv.z * scale * wv.z;
    ov.w = xv.w * scale * wv.w;
    ushort4 pk;
    pk.x = f2bf(ov.x); pk.y = f2bf(ov.y); pk.z = f2bf(ov.z); pk.w = f2bf(ov.w);
    if (TM) {
        size_t addr = ((size_t)(t >> 7) * 16 + (tid >> 4)) * 8192 +
                      (size_t)(t & 127) * 64 + tswz(t, (tid * 4) & 63);
        *reinterpret_cast<ushort4*>(ob + addr) = pk;
    } else {
        *reinterpret_cast<ushort4*>(ob + (size_t)t * DIM + tid * 4) = pk;
    }

    if (ROUTER) {
        int d0 = tid * 4;
        const float* wp = wr + (size_t)d0 * NEXP;
        float pl[8];
        float4 a0 = *reinterpret_cast<const float4*>(wp + 0);
        float4 a1 = *reinterpret_cast<const float4*>(wp + 4);
        float4 b0 = *reinterpret_cast<const float4*>(wp + 8);
        float4 b1 = *reinterpret_cast<const float4*>(wp + 12);
        float4 c0 = *reinterpret_cast<const float4*>(wp + 16);
        float4 c1 = *reinterpret_cast<const float4*>(wp + 20);
        float4 d0v = *reinterpret_cast<const float4*>(wp + 24);
        float4 d1v = *reinterpret_cast<const float4*>(wp + 28);
        pl[0] = ov.x * a0.x + ov.y * b0.x + ov.z * c0.x + ov.w * d0v.x;
        pl[1] = ov.x * a0.y + ov.y * b0.y + ov.z * c0.y + ov.w * d0v.y;
        pl[2] = ov.x * a0.z + ov.y * b0.z + ov.z * c0.z + ov.w * d0v.z;
        pl[3] = ov.x * a0.w + ov.y * b0.w + ov.z * c0.w + ov.w * d0v.w;
        pl[4] = ov.x * a1.x + ov.y * b1.x + ov.z * c1.x + ov.w * d1v.x;
        pl[5] = ov.x * a1.y + ov.y * b1.y + ov.z * c1.y + ov.w * d1v.y;
        pl[6] = ov.x * a1.z + ov.y * b1.z + ov.z * c1.z + ov.w * d1v.z;
        pl[7] = ov.x * a1.w + ov.y * b1.w + ov.z * c1.w + ov.w * d1v.w;
        #pragma unroll
        for (int e = 0; e < 8; ++e) {
            #pragma unroll
            for (int off = 32; off; off >>= 1) pl[e] += __shfl_xor(pl[e], off);
        }
        __shared__ float red2[4][8];
        if ((tid & 63) == 0) {
            #pragma unroll
            for (int e = 0; e < 8; ++e) red2[tid >> 6][e] = pl[e];
        }
        __syncthreads();
        if (tid == 0) {
            float lg[8];
            #pragma unroll
            for (int e = 0; e < 8; ++e)
                lg[e] = red2[0][e] + red2[1][e] + red2[2][e] + red2[3][e];
            float mx = lg[0];
            #pragma unroll
            for (int e = 1; e < 8; ++e) mx = fmaxf(mx, lg[e]);
            float p[8], se = 0.f;
            #pragma unroll
            for (int e = 0; e < 8; ++e) { p[e] = __expf(lg[e] - mx); se += p[e]; }
            float inv = 1.f / se;
            #pragma unroll
            for (int e = 0; e < 8; ++e) p[e] *= inv;
            int i0 = 0;
            #pragma unroll
            for (int e = 1; e < 8; ++e) if (p[e] > p[i0]) i0 = e;
            int i1 = (i0 == 0) ? 1 : 0;
            #pragma unroll
            for (int e = 0; e < 8; ++e) if (e != i0 && p[e] > p[i1]) i1 = e;
            float w0 = p[i0], w1 = p[i1], s = w0 + w1;
            esel[t] = i0 | (i1 << 8);
            wsel[t] = make_float2(w0 / s, w1 / s);
            float z = mx + logf(se);
            zz[t] = z * z;
            #pragma unroll
            for (int e = 0; e < 8; ++e) pp[(size_t)t * 8 + e] = p[e];
        }
    }
}

// ---------------- tconv body: in[K][N] fp32 slab -> out swizzled tile-major [N][K] bf16 ----------------
__device__ __forceinline__ void tconv_body(const float* __restrict__ ip,
                                           u16* __restrict__ op,
                                           int K, int N, int r0, int c0, int t) {
    __shared__ float tile[64][65];
    #pragma unroll
    for (int i = 0; i < 4; ++i) {
        int r = (t >> 4) + i * 16;
        float4 v = *reinterpret_cast<const float4*>(&ip[(size_t)(r0 + r) * N + c0 + (t & 15) * 4]);
        tile[r][(t & 15) * 4 + 0] = v.x;
        tile[r][(t & 15) * 4 + 1] = v.y;
        tile[r][(t & 15) * 4 + 2] = v.z;
        tile[r][(t & 15) * 4 + 3] = v.w;
    }
    __syncthreads();
    int c = t >> 2, rr = (t & 3) * 16;
    short8 v0, v1;
    #pragma unroll
    for (int u = 0; u < 8; ++u) v0[u] = (short)f2bf(tile[rr + u][c]);
    #pragma unroll
    for (int u = 0; u < 8; ++u) v1[u] = (short)f2bf(tile[rr + 8 + u][c]);
    int n = c0 + c;
    int k = r0 + rr;
    size_t tb = ((size_t)(n >> 7) * (K >> 6) + (k >> 6)) * 8192 + (size_t)(n & 127) * 64;
    *reinterpret_cast<short8*>(&op[tb + tswz(n, k & 63)]) = v0;
    *reinterpret_cast<short8*>(&op[tb + tswz(n, (k + 8) & 63)]) = v1;
}

__global__ __launch_bounds__(256) void tconv_k(const float* __restrict__ in,
                                               u16* __restrict__ out,
                                               int K, int N) {
    tconv_body(in, out, K, N, blockIdx.y * 64, blockIdx.x * 64, threadIdx.x);
}

__global__ __launch_bounds__(256) void tconvE_k(const float* __restrict__ w1,
                                                const float* __restrict__ w2,
                                                u16* __restrict__ w1T,
                                                u16* __restrict__ w2T) {
    int bid = blockIdx.x;
    int half = bid >> 13;
    int eb = bid & 8191;
    int e = eb >> 10;
    int t = eb & 1023;
    const size_t ED = (size_t)DIM * FF;
    if (half == 0) {
        int bxx = t & 63, byy = t >> 6;
        tconv_body(w1 + (size_t)e * ED, w1T + (size_t)e * ED,
                   DIM, FF, byy * 64, bxx * 64, threadIdx.x);
    } else {
        int bxx = t & 15, byy = t >> 4;
        tconv_body(w2 + (size_t)e * ED, w2T + (size_t)e * ED,
                   FF, DIM, byy * 64, bxx * 64, threadIdx.x);
    }
}

// ---------------- V transpose per head: vb[B*S][D] bf16 -> vt[BH][64][S] ----------------
__global__ __launch_bounds__(256) void vtrans_k(const u16* __restrict__ vb,
                                                u16* __restrict__ vt) {
    __shared__ u16 tile[64][80];
    int bh = blockIdx.y;
    int b = bh >> 4, h = bh & 15;
    int s0 = blockIdx.x * 64;
    int t = threadIdx.x;
    #pragma unroll
    for (int i = 0; i < 2; ++i) {
        int chunk = i * 256 + t;
        int r = chunk >> 3;
        int c = (chunk & 7) * 8;
        short8 v = *reinterpret_cast<const short8*>(
            &vb[(size_t)(b * SEQ + s0 + r) * DIM + h * HDIM + c]);
        *reinterpret_cast<short8*>(&tile[r][c]) = v;
    }
    __syncthreads();
    int d = t >> 2, s16 = (t & 3) * 16;
    short8 o0, o1;
    #pragma unroll
    for (int u = 0; u < 8; ++u) o0[u] = (short)tile[s16 + u][d];
    #pragma unroll
    for (int u = 0; u < 8; ++u) o1[u] = (short)tile[s16 + 8 + u][d];
    size_t ob = ((size_t)bh * HDIM + d) * SEQ + s0 + s16;
    *reinterpret_cast<short8*>(&vt[ob]) = o0;
    *reinterpret_cast<short8*>(&vt[ob + 8]) = o1;
}

// ---------------- Gather: hg[slot] = h2b[slot_tok[slot]] in swizzled tile-major ----------------
__global__ __launch_bounds__(256) void gather_k(const u16* __restrict__ h2b,
                                                const int* __restrict__ slot_tok,
                                                const int* __restrict__ hdr,
                                                u16* __restrict__ hg) {
    int s = blockIdx.x * 4 + (threadIdx.x >> 6);
    if (s >= (hdr[0] << 7)) return;
    int lane = threadIdx.x & 63;
    int tok = slot_tok[s];
    const short8* src = reinterpret_cast<const short8*>(h2b + (size_t)tok * DIM + lane * 16);
    size_t tb = ((size_t)(s >> 7) * 16 + (lane >> 2)) * 8192 + (size_t)(s & 127) * 64;
    int col = (lane * 16) & 63;
    short8 v0 = src[0], v1 = src[1];
    *reinterpret_cast<short8*>(hg + tb + tswz(s, col)) = v0;
    *reinterpret_cast<short8*>(hg + tb + tswz(s, col + 8)) = v1;
}

// ---------------- MFMA GEMM: swizzled tile-major, XCD supertiling, split-K ----------------
// MODE 0: fused QKV (Bt=concat wqT,wkT,wvT; sel=bx>>3 -> C0/C1/C2 bf16 row-major)
// MODE 1: C0(bf16 partial[ks]) = A@B slice            (wo)
// MODE 2: C0(bf16 swz tile-major) = gelu(A@B); A = hg; Bt = w1T[e]
// MODE 3: C0(bf16 partial[ks] row-major) = A@B slice; A = he; Bt = w2T[e]
template <int MODE, int GX, int SPLITK, int PX>
__global__ __launch_bounds__(256) void mgemm(const u16* __restrict__ A,
                                             const u16* __restrict__ Bt,
                                             void* __restrict__ C0,
                                             void* __restrict__ C1,
                                             void* __restrict__ C2,
                                             const int* __restrict__ hdr,
                                             int K, int N, size_t part_stride) {
    __shared__ __align__(16) u16 As[128 * 64];
    __shared__ __align__(16) u16 Bs[128 * 64];
    const int tid = threadIdx.x;
    const int lane = tid & 63;
    const int w = tid >> 6;
    const int wr = w >> 1, wc = w & 1;
    const int lo = lane & 15, hi = lane >> 4;

    // XCD supertile mapping
    const int PY = 8 / PX;
    const int LBX = GX / PX;
    const int LBY = (int)gridDim.y / PY;
    int f = (int)blockIdx.y * GX + (int)blockIdx.x;
    int xcd = f & 7;
    int j = f >> 3;
    int cx = xcd % PX, cy = xcd / PX;
    int lbx = j % LBX, lby = j / LBX;
    const int bx = cx * LBX + lbx;
    const int by_raw = cy * LBY + lby;
    const int TY = (int)gridDim.y / SPLITK;
    const int ksid = by_raw / TY;
    const int by = by_raw % TY;

    if (MODE >= 2) {
        if (by >= hdr[0]) return;
    }
    const u16* Bbase;
    if (MODE >= 2) {
        int e = hdr[1 + by];
        Bbase = Bt + (size_t)e * N * K + (size_t)bx * 128 * K;
    } else {
        Bbase = Bt + (size_t)bx * 128 * K;
    }
    const size_t row0 = (size_t)by * 128;
    const u16* Abase = A + row0 * K;

    f32x4 acc[4][4];
    #pragma unroll
    for (int m = 0; m < 4; ++m)
        #pragma unroll
        for (int n = 0; n < 4; ++n) acc[m][n] = (f32x4){0.f, 0.f, 0.f, 0.f};

    const int KS = K / SPLITK;
    const int kb = ksid * KS;
    for (int k0 = kb; k0 < kb + KS; k0 += 64) {
        const u16* at = Abase + (size_t)k0 * 128;
        const u16* bt = Bbase + (size_t)k0 * 128;
        #pragma unroll
        for (int i = 0; i < 4; ++i) {
            int chunk = i * 256 + tid;
            gl2lds16(at + chunk * 8, &As[chunk * 8]);
        }
        #pragma unroll
        for (int i = 0; i < 4; ++i) {
            int chunk = i * 256 + tid;
            gl2lds16(bt + chunk * 8, &Bs[chunk * 8]);
        }
        __syncthreads();
        #pragma unroll
        for (int ks = 0; ks < 2; ++ks) {
            short8 a[4], b[4];
            #pragma unroll
            for (int m = 0; m < 4; ++m) {
                int row = wr * 64 + m * 16 + lo;
                a[m] = *reinterpret_cast<const short8*>(
                    &As[row * 64 + tswz(row, ks * 32 + hi * 8)]);
            }
            #pragma unroll
            for (int n = 0; n < 4; ++n) {
                int row = wc * 64 + n * 16 + lo;
                b[n] = *reinterpret_cast<const short8*>(
                    &Bs[row * 64 + tswz(row, ks * 32 + hi * 8)]);
            }
            #pragma unroll
            for (int m = 0; m < 4; ++m)
                #pragma unroll
                for (int n = 0; n < 4; ++n)
                    acc[m][n] = __builtin_amdgcn_mfma_f32_16x16x32_bf16(a[m], b[n], acc[m][n], 0, 0, 0);
        }
        __syncthreads();
    }

    u16* Pf = (u16*)C0 + (size_t)ksid * part_stride;
    #pragma unroll
    for (int m = 0; m < 4; ++m) {
        #pragma unroll
        for (int j2 = 0; j2 < 4; ++j2) {
            int rloc = wr * 64 + m * 16 + hi * 4 + j2;
            size_t r = row0 + rloc;
            #pragma unroll
            for (int n = 0; n < 4; ++n) {
                float v = acc[m][n][j2];
                if (MODE == 0) {
                    int sel = bx >> 3;
                    size_t ccl = (size_t)((bx & 7) * 128 + wc * 64 + n * 16 + lo);
                    u16* Cp = (sel == 0) ? (u16*)C0 : (sel == 1) ? (u16*)C1 : (u16*)C2;
                    Cp[r * N + ccl] = f2bf(v);
                } else if (MODE == 2) {
                    size_t tile = (size_t)by * (N >> 6) + (size_t)bx * 2 + wc;
                    ((u16*)C0)[tile * 8192 + (size_t)rloc * 64 + tswz(rloc, n * 16 + lo)] =
                        f2bf(gelu_fast(v));
                } else {
                    size_t cc = (size_t)(bx * 128 + wc * 64 + n * 16 + lo);
                    Pf[r * N + cc] = f2bf(v);
                }
            }
        }
    }
}

// ---------------- Flash attention (LDS-staged K/V, online softmax, swz ctx out) ----------------
__global__ __launch_bounds__(256) void fattn(const u16* __restrict__ Q,
                                             const u16* __restrict__ Kb,
                                             const u16* __restrict__ Vt,
                                             u16* __restrict__ O) {
    __shared__ __align__(16) char Ks[64 * 128];
    __shared__ __align__(16) char Vs[64 * 128];
    __shared__ __align__(16) char Ps[4][16 * 128];
    const int tid = threadIdx.x, lane = tid & 63, w = tid >> 6;
    const int lo = lane & 15, hi = lane >> 4;
    int fb = (int)blockIdx.x;
    fb = (fb & 7) * ((NBATCH * NHEAD * (SEQ / 64)) >> 3) + (fb >> 3);
    const int qt = fb & 15;
    const int bh = fb >> 4;
    const int b = bh >> 4, h = bh & 15;

    size_t qtok = (size_t)(b * SEQ + qt * 64 + w * 16 + lo);
    short8 qf[2];
    #pragma unroll
    for (int ks = 0; ks < 2; ++ks)
        qf[ks] = *reinterpret_cast<const short8*>(&Q[qtok * DIM + h * HDIM + ks * 32 + hi * 8]);

    float m_r[4], l_r[4];
    f32x4 oa[4];
    #pragma unroll
    for (int j = 0; j < 4; ++j) { m_r[j] = -1e30f; l_r[j] = 0.f; }
    #pragma unroll
    for (int n = 0; n < 4; ++n) oa[n] = (f32x4){0.f, 0.f, 0.f, 0.f};

    const size_t kbase = ((size_t)b * SEQ) * DIM + h * HDIM;
    const size_t vbase = ((size_t)bh * HDIM) * SEQ;
    char* P = Ps[w];

    for (int kt = 0; kt < 16; ++kt) {
        __syncthreads();
        #pragma unroll
        for (int i = 0; i < 2; ++i) {
            int chunk = i * 256 + tid;
            int r = chunk >> 3;
            int cb = (chunk & 7) << 4;
            short8 v = *reinterpret_cast<const short8*>(
                &Kb[kbase + (size_t)(kt * 64 + r) * DIM + (cb >> 1)]);
            *reinterpret_cast<short8*>(&Ks[r * 128 + (cb ^ ((r & 7) << 4))]) = v;
        }
        #pragma unroll
        for (int i = 0; i < 2; ++i) {
            int chunk = i * 256 + tid;
            int r = chunk >> 3;
            int cb = (chunk & 7) << 4;
            short8 v = *reinterpret_cast<const short8*>(
                &Vt[vbase + (size_t)r * SEQ + kt * 64 + (cb >> 1)]);
            *reinterpret_cast<short8*>(&Vs[r * 128 + (cb ^ ((r & 7) << 4))]) = v;
        }
        __syncthreads();

        f32x4 s[4];
        #pragma unroll
        for (int n = 0; n < 4; ++n) {
            f32x4 z = {0.f, 0.f, 0.f, 0.f};
            #pragma unroll
            for (int ks = 0; ks < 2; ++ks) {
                int row = n * 16 + lo;
                int cb = (ks * 32 + hi * 8) * 2;
                short8 kf = *reinterpret_cast<const short8*>(
                    &Ks[row * 128 + (cb ^ ((row & 7) << 4))]);
                z = __builtin_amdgcn_mfma_f32_16x16x32_bf16(qf[ks], kf, z, 0, 0, 0);
            }
            s[n] = z * 0.125f;
        }

        float mx[4];
        #pragma unroll
        for (int j = 0; j < 4; ++j) {
            mx[j] = fmaxf(fmaxf(s[0][j], s[1][j]), fmaxf(s[2][j], s[3][j]));
            #pragma unroll
            for (int off = 1; off < 16; off <<= 1) mx[j] = fmaxf(mx[j], __shfl_xor(mx[j], off));
        }
        float corr[4], rsum[4];
        #pragma unroll
        for (int j = 0; j < 4; ++j) {
            float mn = fmaxf(m_r[j], mx[j]);
            corr[j] = __expf(m_r[j] - mn);
            m_r[j] = mn;
            rsum[j] = 0.f;
        }
        #pragma unroll
        for (int n = 0; n < 4; ++n)
            #pragma unroll
            for (int j = 0; j < 4; ++j) {
                float p = __expf(s[n][j] - m_r[j]);
                s[n][j] = p;
                rsum[j] += p;
            }
        #pragma unroll
        for (int j = 0; j < 4; ++j) {
            #pragma unroll
            for (int off = 1; off < 16; off <<= 1) rsum[j] += __shfl_xor(rsum[j], off);
            l_r[j] = l_r[j] * corr[j] + rsum[j];
        }
        #pragma unroll
        for (int n = 0; n < 4; ++n)
            #pragma unroll
            for (int j = 0; j < 4; ++j) oa[n][j] *= corr[j];

        #pragma unroll
        for (int n = 0; n < 4; ++n)
            #pragma unroll
            for (int j = 0; j < 4; ++j) {
                int q = hi * 4 + j;
                int key = n * 16 + lo;
                *reinterpret_cast<u16*>(&P[q * 128 + ((key * 2) ^ ((q & 7) << 4))]) =
                    f2bf(s[n][j]);
            }

        #pragma unroll
        for (int ks = 0; ks < 2; ++ks) {
            int keyb = (ks * 32 + hi * 8) * 2;
            short8 pf = *reinterpret_cast<const short8*>(
                &P[lo * 128 + (keyb ^ ((lo & 7) << 4))]);
            #pragma unroll
            for (int n = 0; n < 4; ++n) {
                int d = n * 16 + lo;
                short8 vf = *reinterpret_cast<const short8*>(
                    &Vs[d * 128 + (keyb ^ ((d & 7) << 4))]);
                oa[n] = __builtin_amdgcn_mfma_f32_16x16x32_bf16(pf, vf, oa[n], 0, 0, 0);
            }
        }
    }

    #pragma unroll
    for (int j = 0; j < 4; ++j) l_r[j] = 1.f / l_r[j];
    int otok = b * SEQ + qt * 64 + w * 16;
    #pragma unroll
    for (int n = 0; n < 4; ++n)
        #pragma unroll
        for (int j = 0; j < 4; ++j) {
            int r = otok + hi * 4 + j;
            size_t addr = ((size_t)(r >> 7) * 16 + h) * 8192 +
                          (size_t)(r & 127) * 64 + tswz(r, n * 16 + lo);
            O[addr] = f2bf(oa[n][j] * l_r[j]);
        }
}

// ---------------- Scheduler + loss ----------------
__global__ __launch_bounds__(256) void sched_k(const int* __restrict__ esel,
                                               const float2* __restrict__ wsel,
                                               const float* __restrict__ zz,
                                               const float* __restrict__ pp,
                                               int* __restrict__ hdr,
                                               int* __restrict__ slot_tok,
                                               float* __restrict__ slot_w,
                                               int2* __restrict__ tslot,
                                               float* __restrict__ loss_out) {
    __shared__ int cnt[8], base[8], cur[8], tot_s;
    __shared__ float lred[4][9];
    int tid = threadIdx.x;
    if (tid < 8) { cnt[tid] = 0; cur[tid] = 0; }
    __syncthreads();
    for (int t = tid; t < TOKS; t += 256) {
        int es = esel[t];
        atomicAdd(&cnt[es & 255], 1);
        atomicAdd(&cnt[(es >> 8) & 255], 1);
    }
    __syncthreads();
    if (tid == 0) {
        int run = 0;
        for (int e = 0; e < 8; ++e) {
            base[e] = run;
            run += (cnt[e] + 127) & ~127;
        }
        tot_s = run;
        hdr[0] = run >> 7;
    }
    __syncthreads();
    int ntiles = tot_s >> 7;
    for (int T = tid; T < ntiles; T += 256) {
        int r = T << 7;
        int e = 0;
        for (int k = 1; k < 8; ++k) if (r >= base[k]) e = k;
        hdr[1 + T] = e;
    }
    for (int t = tid; t < TOKS; t += 256) {
        int es = esel[t];
        float2 ww = wsel[t];
        int e0 = es & 255, e1 = (es >> 8) & 255;
        int s0 = base[e0] + atomicAdd(&cur[e0], 1);
        slot_tok[s0] = t; slot_w[s0] = ww.x;
        int s1 = base[e1] + atomicAdd(&cur[e1], 1);
        slot_tok[s1] = t; slot_w[s1] = ww.y;
        tslot[t] = make_int2(s0, s1);
    }
    __syncthreads();
    for (int idx = tid; idx < 8 * 128; idx += 256) {
        int e = idx >> 7, p2 = idx & 127;
        int c = cnt[e];
        int al = (c + 127) & ~127;
        if (c + p2 < al) {
            int s = base[e] + c + p2;
            slot_tok[s] = 0;
            slot_w[s] = 0.f;
        }
    }
    // router loss
    float sz = 0.f, sp[8] = {0, 0, 0, 0, 0, 0, 0, 0};
    for (int t = tid; t < TOKS; t += 256) {
        sz += zz[t];
        #pragma unroll
        for (int e = 0; e < 8; ++e) sp[e] += pp[(size_t)t * 8 + e];
    }
    #pragma unroll
    for (int off = 32; off; off >>= 1) {
        sz += __shfl_xor(sz, off);
        #pragma unroll
        for (int e = 0; e < 8; ++e) sp[e] += __shfl_xor(sp[e], off);
    }
    if ((tid & 63) == 0) {
        lred[tid >> 6][0] = sz;
        #pragma unroll
        for (int e = 0; e < 8; ++e) lred[tid >> 6][1 + e] = sp[e];
    }
    __syncthreads();
    if (tid == 0) {
        float tz = lred[0][0] + lred[1][0] + lred[2][0] + lred[3][0];
        float loss = 0.001f * (tz / (float)TOKS);
        float s = 0.f;
        for (int e = 0; e < 8; ++e) {
            float mp = (lred[0][1 + e] + lred[1][1 + e] + lred[2][1 + e] + lred[3][1 + e]) / (float)TOKS;
            s += mp * ((float)cnt[e] / (float)TOKS);
        }
        loss_out[0] = loss + (float)NEXP * s;
    }
}

// ---------------- Combine MoE: xo[tok] += sum over NP bf16 K-partials, 2 slots ----------------
template <int NP>
__global__ __launch_bounds__(256) void combine_k(const u16* __restrict__ accP,
                                                 const int2* __restrict__ tslot,
                                                 const float2* __restrict__ wsel,
                                                 float* __restrict__ xo) {
    int t = blockIdx.x;
    int d4 = threadIdx.x * 4;
    int2 s = tslot[t];
    float2 w = wsel[t];
    const size_t PS = (size_t)MAXSLOTS * DIM;
    float ax = 0.f, ay = 0.f, az = 0.f, aw = 0.f;
    float bxs = 0.f, bys = 0.f, bzs = 0.f, bws = 0.f;
    #pragma unroll
    for (int p = 0; p < NP; ++p) {
        ushort4 a = *reinterpret_cast<const ushort4*>(accP + p * PS + (size_t)s.x * DIM + d4);
        ushort4 b = *reinterpret_cast<const ushort4*>(accP + p * PS + (size_t)s.y * DIM + d4);
        ax += bf2f(a.x); ay += bf2f(a.y); az += bf2f(a.z); aw += bf2f(a.w);
        bxs += bf2f(b.x); bys += bf2f(b.y); bzs += bf2f(b.z); bws += bf2f(b.w);
    }
    float4 o = *reinterpret_cast<const float4*>(xo + (size_t)t * DIM + d4);
    o.x += w.x * ax + w.y * bxs;
    o.y += w.x * ay + w.y * bys;
    o.z += w.x * az + w.y * bzs;
    o.w += w.x * aw + w.y * bws;
    *reinterpret_cast<float4*>(xo + (size_t)t * DIM + d4) = o;
}

extern "C" void kernel_launch(void* const* d_in, const int* in_sizes, int n_in,
                              void* d_out, int out_size, void* d_ws, size_t ws_size,
                              hipStream_t stream) {
    const float* x    = (const float*)d_in[0];
    const float* ln1w = (const float*)d_in[1];
    const float* ln2w = (const float*)d_in[2];
    const float* wq   = (const float*)d_in[3];
    const float* wk   = (const float*)d_in[4];
    const float* wv   = (const float*)d_in[5];
    const float* wo   = (const float*)d_in[6];
    const float* wr   = (const float*)d_in[7];
    const float* w1   = (const float*)d_in[8];
    const float* w2   = (const float*)d_in[9];
    float* xo = (float*)d_out;

    const size_t NTD = (size_t)TOKS * DIM;
    const size_t MB = 1024 * 1024;
    char* p = (char*)d_ws;

    // ---- persistent region ----
    u16* wqkvT = (u16*)p;                       // 6 MB
    u16* woT   = wqkvT + 3 * MB;                // 2 MB
    u16* h2b   = woT + MB;                      // 8 MB
    int* hdr      = (int*)(h2b + NTD);
    int* slot_tok = hdr + 128;
    float* slot_w = (float*)(slot_tok + MAXSLOTS);
    int* esel     = (int*)(slot_w + MAXSLOTS);
    float2* wsel  = (float2*)(esel + TOKS);
    int2* tslot   = (int2*)(wsel + TOKS);
    float* zz     = (float*)(tslot + TOKS);
    float* pp     = zz + TOKS;

    // ---- union region U ----
    char* U = (char*)(pp + TOKS * 8) + 256;
    u16* h_bf = (u16*)U;            // swz tile-major
    u16* qb   = h_bf + NTD;         // row-major
    u16* kb   = qb + NTD;
    u16* vb   = kb + NTD;
    u16* vt   = vb + NTD;
    u16* ctx  = vt + NTD;           // swz tile-major
    u16* woP  = (u16*)(U + 72 * MB);                        // [4][NTD] bf16 = 32 MB
    u16* he   = (u16*)U;                                    // 72 MB swz tile-major
    u16* hg   = (u16*)(U + 72 * MB);                        // 18 MB swz tile-major
    u16* w1T  = (u16*)(U + 90 * MB);                        // 64 MB swz tile-major
    u16* w2T  = w1T + (size_t)NEXP * FF * DIM;              // 64 MB
    u16* accP = w2T + (size_t)NEXP * DIM * FF;              // [4][MAXSLOTS][DIM] bf16 = 72 MB

    // 1) attention-path weight transposes
    tconv_k<<<dim3(16, 16), 256, 0, stream>>>(wq, wqkvT,          DIM, DIM);
    tconv_k<<<dim3(16, 16), 256, 0, stream>>>(wk, wqkvT + MB,     DIM, DIM);
    tconv_k<<<dim3(16, 16), 256, 0, stream>>>(wv, wqkvT + 2 * MB, DIM, DIM);
    tconv_k<<<dim3(16, 16), 256, 0, stream>>>(wo, woT,            DIM, DIM);

    // 2) h = rmsnorm(x)
    rmsnorm_k<0, 1, 0><<<TOKS, 256, 0, stream>>>(x, ln1w, h_bf, nullptr, nullptr,
                                                 nullptr, nullptr, nullptr, nullptr, nullptr);

    // 3) fused q,k,v
    mgemm<0, 24, 1, 4><<<dim3(24, TOKS / 128), 256, 0, stream>>>(
        h_bf, wqkvT, qb, kb, vb, nullptr, DIM, DIM, 0);

    // 4) V transpose + flash attention
    vtrans_k<<<dim3(SEQ / 64, NBATCH * NHEAD), 256, 0, stream>>>(vb, vt);
    fattn<<<NBATCH * NHEAD * (SEQ / 64), 256, 0, stream>>>(qb, kb, vt, ctx);

    // 5) wo split-K x4 (bf16 partials)
    mgemm<1, 8, 4, 2><<<dim3(8, (TOKS / 128) * 4), 256, 0, stream>>>(
        ctx, woT, woP, nullptr, nullptr, nullptr, DIM, DIM, NTD);

    // 6) h2 = rmsnorm(x + sum of 4 woP) + fused router; writes x1 to xo
    rmsnorm_k<1, 0, 4><<<TOKS, 256, 0, stream>>>(x, ln2w, h2b, wr, esel, wsel,
                                                 zz, pp, woP, xo);

    // 7) scheduler + router loss
    sched_k<<<1, 256, 0, stream>>>(esel, wsel, zz, pp, hdr, slot_tok, slot_w, tslot, xo + NTD);

    // 8) gather tokens to slot-major swz tile-major hg
    gather_k<<<MAXSLOTS / 4, 256, 0, stream>>>(h2b, slot_tok, hdr, hg);

    // 9) expert-weight transposes
    tconvE_k<<<16384, 256, 0, stream>>>(w1, w2, w1T, w2T);

    // 10) MoE up: he = gelu(hg @ w1[e])
    mgemm<2, 32, 1, 4><<<dim3(FF / 128, MAXTILES), 256, 0, stream>>>(
        hg, w1T, he, nullptr, nullptr, hdr, DIM, FF, 0);

    // 11) MoE down split-K x4 (bf16 partials; each XCD row owns one K-slice)
    mgemm<3, 8, 4, 2><<<dim3(8, MAXTILES * 4), 256, 0, stream>>>(
        he, w2T, accP, nullptr, nullptr, hdr, FF, DIM, (size_t)MAXSLOTS * DIM);

    // 12) combine expert outputs into xo (4 partials)
    combine_k<4><<<TOKS, 256, 0, stream>>>(accP, tslot, wsel, xo);
}